// Round 1
// baseline (2973.678 us; speedup 1.0000x reference)
//
#include <hip/hip_runtime.h>

#define N_NODES 50000
#define N_EDGES 800000
#define IN_DIM 128
#define HID_DIM 128
#define OUT_DIM 64

__global__ void zero_kernel(float* __restrict__ p, int n) {
    int i = blockIdx.x * blockDim.x + threadIdx.x;
    int stride = gridDim.x * blockDim.x;
    for (; i < n; i += stride) p[i] = 0.0f;
}

// out[row[e]][:] += vals[e] * x[col[e]][:]  for D=128, 32 threads/edge, 4 dims/thread
__global__ void spmm_atomic128(const int* __restrict__ row, const int* __restrict__ col,
                               const float* __restrict__ vals, const float* __restrict__ x,
                               float* __restrict__ out) {
    long long gid = (long long)blockIdx.x * blockDim.x + threadIdx.x;
    const long long total = (long long)N_EDGES * 32;
    if (gid >= total) return;
    int e  = (int)(gid >> 5);        // edge index
    int c4 = (int)(gid & 31);        // which 4-dim chunk
    int r = row[e];
    int c = col[e];
    float v = vals[e];
    const float4 xv = *reinterpret_cast<const float4*>(&x[(long long)c * 128 + c4 * 4]);
    float* o = &out[(long long)r * 128 + c4 * 4];
    atomicAdd(o + 0, v * xv.x);
    atomicAdd(o + 1, v * xv.y);
    atomicAdd(o + 2, v * xv.z);
    atomicAdd(o + 3, v * xv.w);
}

// out[i][j] = (relu?) sum_k A[i][k] * W[k][j];  blockDim = (N_COLS, rows_per_block)
template<int K, int NCOL, bool RELU>
__global__ void gemm_small(const float* __restrict__ A, const float* __restrict__ W,
                           float* __restrict__ out, int M) {
    int j = threadIdx.x;
    int i = blockIdx.x * blockDim.y + threadIdx.y;
    if (i >= M) return;
    const float* a = &A[(long long)i * K];
    float acc = 0.0f;
#pragma unroll 8
    for (int k = 0; k < K; ++k) {
        acc += a[k] * W[k * NCOL + j];
    }
    if (RELU) acc = fmaxf(acc, 0.0f);
    out[(long long)i * NCOL + j] = acc;
}

extern "C" void kernel_launch(void* const* d_in, const int* in_sizes, int n_in,
                              void* d_out, int out_size, void* d_ws, size_t ws_size,
                              hipStream_t stream) {
    const float* x    = (const float*)d_in[0];
    const int*   row  = (const int*)  d_in[1];
    const int*   col  = (const int*)  d_in[2];
    const float* vals = (const float*)d_in[3];
    const float* W1   = (const float*)d_in[4];
    const float* W2   = (const float*)d_in[5];
    float* out = (float*)d_out;

    // workspace layout: s [N,128] (spmm accumulator, reused for both layers),
    //                   h [N,128] (layer-1 activations)
    float* s = (float*)d_ws;
    float* h = s + (size_t)N_NODES * HID_DIM;

    const int nfloats = N_NODES * HID_DIM;           // 6.4M
    const long long spmm_threads = (long long)N_EDGES * 32;  // 25.6M
    const int spmm_blocks = (int)((spmm_threads + 255) / 256);

    // ---- layer 1: s = spmm(x); h = relu(s @ W1) ----
    zero_kernel<<<2048, 256, 0, stream>>>(s, nfloats);
    spmm_atomic128<<<spmm_blocks, 256, 0, stream>>>(row, col, vals, x, s);
    gemm_small<IN_DIM, HID_DIM, true>
        <<<(N_NODES + 1) / 2, dim3(HID_DIM, 2), 0, stream>>>(s, W1, h, N_NODES);

    // ---- layer 2: s = spmm(h); out = s @ W2 ----
    zero_kernel<<<2048, 256, 0, stream>>>(s, nfloats);
    spmm_atomic128<<<spmm_blocks, 256, 0, stream>>>(row, col, vals, h, s);
    gemm_small<HID_DIM, OUT_DIM, false>
        <<<(N_NODES + 3) / 4, dim3(OUT_DIM, 4), 0, stream>>>(s, W2, out, N_NODES);
}

// Round 2
// 498.725 us; speedup vs baseline: 5.9626x; 5.9626x over previous
//
#include <hip/hip_runtime.h>

#define N_NODES 50000
#define N_EDGES 800000
#define IN_DIM 128
#define HID_DIM 128
#define OUT_DIM 64

// ---------------- CSR build ----------------

__global__ void zero_ints(int* __restrict__ p, int n) {
    int i = blockIdx.x * blockDim.x + threadIdx.x;
    int stride = gridDim.x * blockDim.x;
    for (; i < n; i += stride) p[i] = 0;
}

__global__ void hist_rows(const int* __restrict__ row, int* __restrict__ counts) {
    int e = blockIdx.x * blockDim.x + threadIdx.x;
    int stride = gridDim.x * blockDim.x;
    for (; e < N_EDGES; e += stride) atomicAdd(&counts[row[e]], 1);
}

// single-block (1024-thread) exclusive scan of counts -> row_ptr (and cursor copy)
__global__ void scan_rowptr(const int* __restrict__ counts, int* __restrict__ row_ptr,
                            int* __restrict__ cursor) {
    __shared__ int sums[1024];
    const int t = threadIdx.x;
    const int CHUNK = (N_NODES + 1023) / 1024;   // 49
    int lo = t * CHUNK;
    int hi = lo + CHUNK; if (hi > N_NODES) hi = N_NODES;
    int s = 0;
    for (int i = lo; i < hi; ++i) s += counts[i];
    sums[t] = s;
    const int mysum = s;
    __syncthreads();
    for (int off = 1; off < 1024; off <<= 1) {
        int v = sums[t];
        int add = (t >= off) ? sums[t - off] : 0;
        __syncthreads();
        sums[t] = v + add;
        __syncthreads();
    }
    int run = sums[t] - mysum;                   // exclusive offset of this chunk
    for (int i = lo; i < hi; ++i) {
        row_ptr[i] = run;
        cursor[i]  = run;
        run += counts[i];
    }
    if (t == 1023) row_ptr[N_NODES] = sums[1023];
}

__global__ void scatter_csr(const int* __restrict__ row, const int* __restrict__ col,
                            const float* __restrict__ vals, int* __restrict__ cursor,
                            int* __restrict__ csr_col, float* __restrict__ csr_val) {
    int e = blockIdx.x * blockDim.x + threadIdx.x;
    int stride = gridDim.x * blockDim.x;
    for (; e < N_EDGES; e += stride) {
        int r = row[e];
        int p = atomicAdd(&cursor[r], 1);
        csr_col[p] = col[e];
        csr_val[p] = vals[e];
    }
}

// ---------------- dense GEMM: out[M,N] = A[M,K] @ W[K,N], W staged in LDS ----------------

template<int K, int N>
__global__ __launch_bounds__(256) void gemm_lds(const float* __restrict__ A,
                                                const float* __restrict__ W,
                                                float* __restrict__ out, int M) {
    constexpr int GROUPS = 256 / N;       // 2 (N=128) or 4 (N=64)
    constexpr int RPT = 4;                // rows per thread
    constexpr int ROWS = GROUPS * RPT;    // 8 or 16 rows per block
    __shared__ float Wlds[K * N];
    for (int i = threadIdx.x; i < (K * N) / 4; i += 256)
        reinterpret_cast<float4*>(Wlds)[i] = reinterpret_cast<const float4*>(W)[i];
    __syncthreads();

    const int j = threadIdx.x % N;
    const int g = threadIdx.x / N;
    const int r0 = blockIdx.x * ROWS + g * RPT;
    if (r0 >= M) return;
    const float* a0 = A + (size_t)r0 * K;

    float acc[RPT] = {0.f, 0.f, 0.f, 0.f};
#pragma unroll 8
    for (int k = 0; k < K; ++k) {
        float w = Wlds[k * N + j];
#pragma unroll
        for (int t = 0; t < RPT; ++t)
            acc[t] = fmaf(a0[(size_t)t * K + k], w, acc[t]);
    }
#pragma unroll
    for (int t = 0; t < RPT; ++t) {
        if (r0 + t < M) out[(size_t)(r0 + t) * N + j] = acc[t];
    }
}

// ---------------- CSR SPMM: out[r,:] = (relu?) sum_e vals[e] * x[col[e],:], 1 wave/row ----------------

template<int D, bool RELU>
__global__ __launch_bounds__(256) void spmm_csr(const int* __restrict__ row_ptr,
                                                const int* __restrict__ csr_col,
                                                const float* __restrict__ csr_val,
                                                const float* __restrict__ x,
                                                float* __restrict__ out) {
    const int wid = threadIdx.x >> 6;
    const int lane = threadIdx.x & 63;
    const int r = blockIdx.x * 4 + wid;
    if (r >= N_NODES) return;
    const int start = row_ptr[r];
    const int end   = row_ptr[r + 1];

    if (D == 128) {
        const float* xb = x + lane * 2;
        float ax0 = 0.f, ay0 = 0.f, ax1 = 0.f, ay1 = 0.f;
        int e = start;
        for (; e + 1 < end; e += 2) {
            int   c0 = csr_col[e],     c1 = csr_col[e + 1];
            float v0 = csr_val[e],     v1 = csr_val[e + 1];
            float2 x0 = *reinterpret_cast<const float2*>(xb + (size_t)c0 * 128);
            float2 x1 = *reinterpret_cast<const float2*>(xb + (size_t)c1 * 128);
            ax0 = fmaf(v0, x0.x, ax0); ay0 = fmaf(v0, x0.y, ay0);
            ax1 = fmaf(v1, x1.x, ax1); ay1 = fmaf(v1, x1.y, ay1);
        }
        if (e < end) {
            int c0 = csr_col[e]; float v0 = csr_val[e];
            float2 x0 = *reinterpret_cast<const float2*>(xb + (size_t)c0 * 128);
            ax0 = fmaf(v0, x0.x, ax0); ay0 = fmaf(v0, x0.y, ay0);
        }
        float rx = ax0 + ax1, ry = ay0 + ay1;
        if (RELU) { rx = fmaxf(rx, 0.f); ry = fmaxf(ry, 0.f); }
        float2 res = {rx, ry};
        *reinterpret_cast<float2*>(out + (size_t)r * 128 + lane * 2) = res;
    } else {  // D == 64
        const float* xb = x + lane;
        float a0 = 0.f, a1 = 0.f;
        int e = start;
        for (; e + 1 < end; e += 2) {
            int   c0 = csr_col[e],  c1 = csr_col[e + 1];
            float v0 = csr_val[e],  v1 = csr_val[e + 1];
            a0 = fmaf(v0, xb[(size_t)c0 * 64], a0);
            a1 = fmaf(v1, xb[(size_t)c1 * 64], a1);
        }
        if (e < end) a0 = fmaf(csr_val[e], xb[(size_t)csr_col[e] * 64], a0);
        float res = a0 + a1;
        if (RELU) res = fmaxf(res, 0.f);
        out[(size_t)r * 64 + lane] = res;
    }
}

// ---------------- launch ----------------

extern "C" void kernel_launch(void* const* d_in, const int* in_sizes, int n_in,
                              void* d_out, int out_size, void* d_ws, size_t ws_size,
                              hipStream_t stream) {
    const float* x    = (const float*)d_in[0];
    const int*   row  = (const int*)  d_in[1];
    const int*   col  = (const int*)  d_in[2];
    const float* vals = (const float*)d_in[3];
    const float* W1   = (const float*)d_in[4];
    const float* W2   = (const float*)d_in[5];
    float* out = (float*)d_out;

    // workspace layout (256B-aligned chunks)
    char* ws = (char*)d_ws;
    auto align = [](size_t v) { return (v + 255) & ~(size_t)255; };
    int*   counts  = (int*)ws;                 ws += align(sizeof(int) * N_NODES);
    int*   row_ptr = (int*)ws;                 ws += align(sizeof(int) * (N_NODES + 1));
    int*   cursor  = (int*)ws;                 ws += align(sizeof(int) * N_NODES);
    int*   csr_col = (int*)ws;                 ws += align(sizeof(int) * N_EDGES);
    float* csr_val = (float*)ws;               ws += align(sizeof(float) * N_EDGES);
    float* tbuf    = (float*)ws;               ws += align(sizeof(float) * N_NODES * HID_DIM);
    float* hbuf    = (float*)ws;               ws += align(sizeof(float) * N_NODES * HID_DIM);

    // ---- CSR build (used by both layers) ----
    zero_ints<<<196, 256, 0, stream>>>(counts, N_NODES);
    hist_rows<<<1024, 256, 0, stream>>>(row, counts);
    scan_rowptr<<<1, 1024, 0, stream>>>(counts, row_ptr, cursor);
    scatter_csr<<<1024, 256, 0, stream>>>(row, col, vals, cursor, csr_col, csr_val);

    // ---- layer 1: h = relu( A @ (x @ W1) ) ----
    gemm_lds<IN_DIM, HID_DIM><<<(N_NODES + 7) / 8, 256, 0, stream>>>(x, W1, tbuf, N_NODES);
    spmm_csr<HID_DIM, true><<<(N_NODES + 3) / 4, 256, 0, stream>>>(row_ptr, csr_col, csr_val, tbuf, hbuf);

    // ---- layer 2: out = A @ (h @ W2) ----
    gemm_lds<HID_DIM, OUT_DIM><<<(N_NODES + 15) / 16, 256, 0, stream>>>(hbuf, W2, tbuf, N_NODES);
    spmm_csr<OUT_DIM, false><<<(N_NODES + 3) / 4, 256, 0, stream>>>(row_ptr, csr_col, csr_val, tbuf, out);
}

// Round 3
// 392.830 us; speedup vs baseline: 7.5699x; 1.2696x over previous
//
#include <hip/hip_runtime.h>

#define N_NODES 50000
#define N_EDGES 800000
#define IN_DIM 128
#define HID_DIM 128
#define OUT_DIM 64

// ---------------- CSR build ----------------

__global__ void zero_ints(int* __restrict__ p, int n) {
    int i = blockIdx.x * blockDim.x + threadIdx.x;
    int stride = gridDim.x * blockDim.x;
    for (; i < n; i += stride) p[i] = 0;
}

__global__ void hist_rows(const int* __restrict__ row, int* __restrict__ counts) {
    int e = blockIdx.x * blockDim.x + threadIdx.x;
    int stride = gridDim.x * blockDim.x;
    for (; e < N_EDGES; e += stride) atomicAdd(&counts[row[e]], 1);
}

// single-block (1024-thread) exclusive scan of counts -> row_ptr (and cursor copy)
__global__ void scan_rowptr(const int* __restrict__ counts, int* __restrict__ row_ptr,
                            int* __restrict__ cursor) {
    __shared__ int sums[1024];
    const int t = threadIdx.x;
    const int CHUNK = (N_NODES + 1023) / 1024;   // 49
    int lo = t * CHUNK;
    int hi = lo + CHUNK; if (hi > N_NODES) hi = N_NODES;
    int s = 0;
    for (int i = lo; i < hi; ++i) s += counts[i];
    sums[t] = s;
    const int mysum = s;
    __syncthreads();
    for (int off = 1; off < 1024; off <<= 1) {
        int v = sums[t];
        int add = (t >= off) ? sums[t - off] : 0;
        __syncthreads();
        sums[t] = v + add;
        __syncthreads();
    }
    int run = sums[t] - mysum;                   // exclusive offset of this chunk
    for (int i = lo; i < hi; ++i) {
        row_ptr[i] = run;
        cursor[i]  = run;
        run += counts[i];
    }
    if (t == 1023) row_ptr[N_NODES] = sums[1023];
}

__global__ void scatter_csr(const int* __restrict__ row, const int* __restrict__ col,
                            const float* __restrict__ vals, int* __restrict__ cursor,
                            int* __restrict__ csr_col, float* __restrict__ csr_val) {
    int e = blockIdx.x * blockDim.x + threadIdx.x;
    int stride = gridDim.x * blockDim.x;
    for (; e < N_EDGES; e += stride) {
        int r = row[e];
        int p = atomicAdd(&cursor[r], 1);
        csr_col[p] = col[e];
        csr_val[p] = vals[e];
    }
}

// ---------------- dense GEMM: out[M,N] = A[M,128] @ W[128,N] ----------------
// BM=64, BN=64, K=128 full. A transposed into LDS, W tile k-major in LDS.
// 256 threads as 16x16, each computes a 4x4 micro-tile. 64 KB LDS -> 2 blocks/CU.

template<int N>
__global__ __launch_bounds__(256) void gemm_tile(const float* __restrict__ A,
                                                 const float* __restrict__ W,
                                                 float* __restrict__ out, int M) {
    __shared__ float At[128][64];   // At[k][m]
    __shared__ float Wt[128][64];   // Wt[k][n]
    const int tid = threadIdx.x;
    const int r0  = blockIdx.x * 64;
    const int bn0 = blockIdx.y * 64;

    // stage W tile: 128 rows x 16 float4, coalesced read, contiguous LDS write
#pragma unroll
    for (int it = 0; it < 8; ++it) {
        int f4 = tid + it * 256;          // 0..2047
        int k = f4 >> 4, c = f4 & 15;
        float4 w = *reinterpret_cast<const float4*>(&W[(size_t)k * N + bn0 + c * 4]);
        *reinterpret_cast<float4*>(&Wt[k][c * 4]) = w;
    }

    // stage A tile transposed: lane = row, wave = k-quarter
    {
        const int m  = tid & 63;
        const int kq = tid >> 6;          // 0..3
        const int r  = r0 + m;
        const bool valid = r < M;
        const float* Ar = A + (size_t)r * 128 + kq * 32;
#pragma unroll
        for (int it = 0; it < 8; ++it) {
            float4 a = {0.f, 0.f, 0.f, 0.f};
            if (valid) a = *reinterpret_cast<const float4*>(&Ar[it * 4]);
            int k = kq * 32 + it * 4;
            At[k + 0][m] = a.x;
            At[k + 1][m] = a.y;
            At[k + 2][m] = a.z;
            At[k + 3][m] = a.w;
        }
    }
    __syncthreads();

    const int tx = tid & 15;              // n group
    const int ty = tid >> 4;              // m group
    float acc[4][4];
#pragma unroll
    for (int i = 0; i < 4; ++i)
#pragma unroll
        for (int j = 0; j < 4; ++j) acc[i][j] = 0.f;

#pragma unroll 4
    for (int k = 0; k < 128; ++k) {
        float4 a = *reinterpret_cast<const float4*>(&At[k][ty * 4]);
        float4 w = *reinterpret_cast<const float4*>(&Wt[k][tx * 4]);
        acc[0][0] = fmaf(a.x, w.x, acc[0][0]); acc[0][1] = fmaf(a.x, w.y, acc[0][1]);
        acc[0][2] = fmaf(a.x, w.z, acc[0][2]); acc[0][3] = fmaf(a.x, w.w, acc[0][3]);
        acc[1][0] = fmaf(a.y, w.x, acc[1][0]); acc[1][1] = fmaf(a.y, w.y, acc[1][1]);
        acc[1][2] = fmaf(a.y, w.z, acc[1][2]); acc[1][3] = fmaf(a.y, w.w, acc[1][3]);
        acc[2][0] = fmaf(a.z, w.x, acc[2][0]); acc[2][1] = fmaf(a.z, w.y, acc[2][1]);
        acc[2][2] = fmaf(a.z, w.z, acc[2][2]); acc[2][3] = fmaf(a.z, w.w, acc[2][3]);
        acc[3][0] = fmaf(a.w, w.x, acc[3][0]); acc[3][1] = fmaf(a.w, w.y, acc[3][1]);
        acc[3][2] = fmaf(a.w, w.z, acc[3][2]); acc[3][3] = fmaf(a.w, w.w, acc[3][3]);
    }

#pragma unroll
    for (int i = 0; i < 4; ++i) {
        int r = r0 + ty * 4 + i;
        if (r < M) {
            float4 v = {acc[i][0], acc[i][1], acc[i][2], acc[i][3]};
            *reinterpret_cast<float4*>(&out[(size_t)r * N + bn0 + tx * 4]) = v;
        }
    }
}

// ---------------- CSR SPMM: out[r,:] = (relu?) sum_e vals[e] * x[col[e],:], 1 wave/row ----------------

template<int D, bool RELU>
__global__ __launch_bounds__(256) void spmm_csr(const int* __restrict__ row_ptr,
                                                const int* __restrict__ csr_col,
                                                const float* __restrict__ csr_val,
                                                const float* __restrict__ x,
                                                float* __restrict__ out) {
    const int wid = threadIdx.x >> 6;
    const int lane = threadIdx.x & 63;
    const int r = blockIdx.x * 4 + wid;
    if (r >= N_NODES) return;
    const int start = row_ptr[r];
    const int end   = row_ptr[r + 1];

    if (D == 128) {
        const float* xb = x + lane * 2;
        float ax0 = 0.f, ay0 = 0.f, ax1 = 0.f, ay1 = 0.f;
        int e = start;
        for (; e + 1 < end; e += 2) {
            int   c0 = csr_col[e],     c1 = csr_col[e + 1];
            float v0 = csr_val[e],     v1 = csr_val[e + 1];
            float2 x0 = *reinterpret_cast<const float2*>(xb + (size_t)c0 * 128);
            float2 x1 = *reinterpret_cast<const float2*>(xb + (size_t)c1 * 128);
            ax0 = fmaf(v0, x0.x, ax0); ay0 = fmaf(v0, x0.y, ay0);
            ax1 = fmaf(v1, x1.x, ax1); ay1 = fmaf(v1, x1.y, ay1);
        }
        if (e < end) {
            int c0 = csr_col[e]; float v0 = csr_val[e];
            float2 x0 = *reinterpret_cast<const float2*>(xb + (size_t)c0 * 128);
            ax0 = fmaf(v0, x0.x, ax0); ay0 = fmaf(v0, x0.y, ay0);
        }
        float rx = ax0 + ax1, ry = ay0 + ay1;
        if (RELU) { rx = fmaxf(rx, 0.f); ry = fmaxf(ry, 0.f); }
        float2 res = {rx, ry};
        *reinterpret_cast<float2*>(out + (size_t)r * 128 + lane * 2) = res;
    } else {  // D == 64
        const float* xb = x + lane;
        float a0 = 0.f, a1 = 0.f;
        int e = start;
        for (; e + 1 < end; e += 2) {
            int   c0 = csr_col[e],  c1 = csr_col[e + 1];
            float v0 = csr_val[e],  v1 = csr_val[e + 1];
            a0 = fmaf(v0, xb[(size_t)c0 * 64], a0);
            a1 = fmaf(v1, xb[(size_t)c1 * 64], a1);
        }
        if (e < end) a0 = fmaf(csr_val[e], xb[(size_t)csr_col[e] * 64], a0);
        float res = a0 + a1;
        if (RELU) res = fmaxf(res, 0.f);
        out[(size_t)r * 64 + lane] = res;
    }
}

// ---------------- launch ----------------

extern "C" void kernel_launch(void* const* d_in, const int* in_sizes, int n_in,
                              void* d_out, int out_size, void* d_ws, size_t ws_size,
                              hipStream_t stream) {
    const float* x    = (const float*)d_in[0];
    const int*   row  = (const int*)  d_in[1];
    const int*   col  = (const int*)  d_in[2];
    const float* vals = (const float*)d_in[3];
    const float* W1   = (const float*)d_in[4];
    const float* W2   = (const float*)d_in[5];
    float* out = (float*)d_out;

    // workspace layout (256B-aligned chunks)
    char* ws = (char*)d_ws;
    auto align = [](size_t v) { return (v + 255) & ~(size_t)255; };
    int*   counts  = (int*)ws;                 ws += align(sizeof(int) * N_NODES);
    int*   row_ptr = (int*)ws;                 ws += align(sizeof(int) * (N_NODES + 1));
    int*   cursor  = (int*)ws;                 ws += align(sizeof(int) * N_NODES);
    int*   csr_col = (int*)ws;                 ws += align(sizeof(int) * N_EDGES);
    float* csr_val = (float*)ws;               ws += align(sizeof(float) * N_EDGES);
    float* tbuf    = (float*)ws;               ws += align(sizeof(float) * N_NODES * HID_DIM);
    float* hbuf    = (float*)ws;               ws += align(sizeof(float) * N_NODES * HID_DIM);

    // ---- CSR build (used by both layers) ----
    zero_ints<<<196, 256, 0, stream>>>(counts, N_NODES);
    hist_rows<<<1024, 256, 0, stream>>>(row, counts);
    scan_rowptr<<<1, 1024, 0, stream>>>(counts, row_ptr, cursor);
    scatter_csr<<<1024, 256, 0, stream>>>(row, col, vals, cursor, csr_col, csr_val);

    // ---- layer 1: h = relu( A @ (x @ W1) ) ----
    gemm_tile<HID_DIM><<<dim3((N_NODES + 63) / 64, HID_DIM / 64), 256, 0, stream>>>(x, W1, tbuf, N_NODES);
    spmm_csr<HID_DIM, true><<<(N_NODES + 3) / 4, 256, 0, stream>>>(row_ptr, csr_col, csr_val, tbuf, hbuf);

    // ---- layer 2: out = A @ (h @ W2) ----
    gemm_tile<OUT_DIM><<<dim3((N_NODES + 63) / 64, OUT_DIM / 64), 256, 0, stream>>>(hbuf, W2, tbuf, N_NODES);
    spmm_csr<OUT_DIM, false><<<(N_NODES + 3) / 4, 256, 0, stream>>>(row_ptr, csr_col, csr_val, tbuf, out);
}

// Round 4
// 277.690 us; speedup vs baseline: 10.7086x; 1.4146x over previous
//
#include <hip/hip_runtime.h>

#define N_NODES 50000
#define N_EDGES 800000
#define IN_DIM 128
#define HID_DIM 128
#define OUT_DIM 64

#define SCAN_BLOCKS 64
#define SCAN_THREADS 256
#define SCAN_CH 4        // 64*256*4 = 65536 >= N_NODES

// ---------------- CSR build ----------------

__global__ void zero_ints(int* __restrict__ p, int n) {
    int i = blockIdx.x * blockDim.x + threadIdx.x;
    int stride = gridDim.x * blockDim.x;
    for (; i < n; i += stride) p[i] = 0;
}

__global__ void hist_rows(const int* __restrict__ row, int* __restrict__ counts) {
    int e = blockIdx.x * blockDim.x + threadIdx.x;
    int stride = gridDim.x * blockDim.x;
    for (; e < N_EDGES; e += stride) atomicAdd(&counts[row[e]], 1);
}

// scan stage 1: per-block partial sums of counts
__global__ __launch_bounds__(SCAN_THREADS) void scan_part(const int* __restrict__ counts,
                                                          int* __restrict__ bsum) {
    __shared__ int red[SCAN_THREADS];
    const int b = blockIdx.x, t = threadIdx.x;
    const int base = (b * SCAN_THREADS + t) * SCAN_CH;
    int s = 0;
#pragma unroll
    for (int i = 0; i < SCAN_CH; ++i) {
        int idx = base + i;
        if (idx < N_NODES) s += counts[idx];
    }
    red[t] = s;
    __syncthreads();
#pragma unroll
    for (int off = SCAN_THREADS / 2; off > 0; off >>= 1) {
        if (t < off) red[t] += red[t + off];
        __syncthreads();
    }
    if (t == 0) bsum[b] = red[0];
}

// scan stage 2: one-wave exclusive scan of the 64 block sums
__global__ void scan_bsum(const int* __restrict__ bsum, int* __restrict__ boff) {
    const int t = threadIdx.x;     // 0..63
    int orig = bsum[t];
    int v = orig;
#pragma unroll
    for (int off = 1; off < 64; off <<= 1) {
        int u = __shfl_up(v, off, 64);
        if (t >= off) v += u;
    }
    boff[t] = v - orig;            // exclusive prefix
}

// scan stage 3: per-block rescan + write row_ptr / cursor
__global__ __launch_bounds__(SCAN_THREADS) void scan_final(const int* __restrict__ counts,
                                                           const int* __restrict__ boff,
                                                           int* __restrict__ row_ptr,
                                                           int* __restrict__ cursor) {
    __shared__ int sums[SCAN_THREADS];
    const int b = blockIdx.x, t = threadIdx.x;
    const int base = (b * SCAN_THREADS + t) * SCAN_CH;
    int local[SCAN_CH];
    int s = 0;
#pragma unroll
    for (int i = 0; i < SCAN_CH; ++i) {
        int idx = base + i;
        int c = (idx < N_NODES) ? counts[idx] : 0;
        local[i] = c;
        s += c;
    }
    sums[t] = s;
    __syncthreads();
#pragma unroll
    for (int off = 1; off < SCAN_THREADS; off <<= 1) {
        int v = sums[t];
        int add = (t >= off) ? sums[t - off] : 0;
        __syncthreads();
        sums[t] = v + add;
        __syncthreads();
    }
    int run = boff[b] + sums[t] - s;   // global exclusive prefix for this thread's chunk
#pragma unroll
    for (int i = 0; i < SCAN_CH; ++i) {
        int idx = base + i;
        if (idx < N_NODES) {
            row_ptr[idx] = run;
            cursor[idx]  = run;
            run += local[i];
        }
    }
    if (b == 0 && t == 0) row_ptr[N_NODES] = N_EDGES;
}

// scatter edges into packed CSR: int2 {col, float_bits(val)}
__global__ void scatter_csr(const int* __restrict__ row, const int* __restrict__ col,
                            const float* __restrict__ vals, int* __restrict__ cursor,
                            int2* __restrict__ csr) {
    int e = blockIdx.x * blockDim.x + threadIdx.x;
    int stride = gridDim.x * blockDim.x;
    for (; e < N_EDGES; e += stride) {
        int r = row[e];
        int p = atomicAdd(&cursor[r], 1);
        int2 pk = { col[e], __float_as_int(vals[e]) };
        csr[p] = pk;
    }
}

// ---------------- dense GEMM: out[M,N] = A[M,128] @ W[128,N] ----------------
// BM=64, BN=64, K=128 full. A transposed into LDS, W tile k-major in LDS.
// 256 threads as 16x16, each computes a 4x4 micro-tile. 64 KB LDS -> 2 blocks/CU.

template<int N>
__global__ __launch_bounds__(256) void gemm_tile(const float* __restrict__ A,
                                                 const float* __restrict__ W,
                                                 float* __restrict__ out, int M) {
    __shared__ float At[128][64];   // At[k][m]
    __shared__ float Wt[128][64];   // Wt[k][n]
    const int tid = threadIdx.x;
    const int r0  = blockIdx.x * 64;
    const int bn0 = blockIdx.y * 64;

    // stage W tile: 128 rows x 16 float4, coalesced read, contiguous LDS write
#pragma unroll
    for (int it = 0; it < 8; ++it) {
        int f4 = tid + it * 256;          // 0..2047
        int k = f4 >> 4, c = f4 & 15;
        float4 w = *reinterpret_cast<const float4*>(&W[(size_t)k * N + bn0 + c * 4]);
        *reinterpret_cast<float4*>(&Wt[k][c * 4]) = w;
    }

    // stage A tile transposed: lane = row, wave = k-quarter
    {
        const int m  = tid & 63;
        const int kq = tid >> 6;          // 0..3
        const int r  = r0 + m;
        const bool valid = r < M;
        const float* Ar = A + (size_t)r * 128 + kq * 32;
#pragma unroll
        for (int it = 0; it < 8; ++it) {
            float4 a = {0.f, 0.f, 0.f, 0.f};
            if (valid) a = *reinterpret_cast<const float4*>(&Ar[it * 4]);
            int k = kq * 32 + it * 4;
            At[k + 0][m] = a.x;
            At[k + 1][m] = a.y;
            At[k + 2][m] = a.z;
            At[k + 3][m] = a.w;
        }
    }
    __syncthreads();

    const int tx = tid & 15;              // n group
    const int ty = tid >> 4;              // m group
    float acc[4][4];
#pragma unroll
    for (int i = 0; i < 4; ++i)
#pragma unroll
        for (int j = 0; j < 4; ++j) acc[i][j] = 0.f;

#pragma unroll 4
    for (int k = 0; k < 128; ++k) {
        float4 a = *reinterpret_cast<const float4*>(&At[k][ty * 4]);
        float4 w = *reinterpret_cast<const float4*>(&Wt[k][tx * 4]);
        acc[0][0] = fmaf(a.x, w.x, acc[0][0]); acc[0][1] = fmaf(a.x, w.y, acc[0][1]);
        acc[0][2] = fmaf(a.x, w.z, acc[0][2]); acc[0][3] = fmaf(a.x, w.w, acc[0][3]);
        acc[1][0] = fmaf(a.y, w.x, acc[1][0]); acc[1][1] = fmaf(a.y, w.y, acc[1][1]);
        acc[1][2] = fmaf(a.y, w.z, acc[1][2]); acc[1][3] = fmaf(a.y, w.w, acc[1][3]);
        acc[2][0] = fmaf(a.z, w.x, acc[2][0]); acc[2][1] = fmaf(a.z, w.y, acc[2][1]);
        acc[2][2] = fmaf(a.z, w.z, acc[2][2]); acc[2][3] = fmaf(a.z, w.w, acc[2][3]);
        acc[3][0] = fmaf(a.w, w.x, acc[3][0]); acc[3][1] = fmaf(a.w, w.y, acc[3][1]);
        acc[3][2] = fmaf(a.w, w.z, acc[3][2]); acc[3][3] = fmaf(a.w, w.w, acc[3][3]);
    }

#pragma unroll
    for (int i = 0; i < 4; ++i) {
        int r = r0 + ty * 4 + i;
        if (r < M) {
            float4 v = {acc[i][0], acc[i][1], acc[i][2], acc[i][3]};
            *reinterpret_cast<float4*>(&out[(size_t)r * N + bn0 + tx * 4]) = v;
        }
    }
}

// ---------------- CSR SPMM: out[r,:] = (relu?) sum_e val[e] * x[col[e],:], 1 wave/row ----------------

template<int D, bool RELU>
__global__ __launch_bounds__(256) void spmm_csr(const int* __restrict__ row_ptr,
                                                const int2* __restrict__ csr,
                                                const float* __restrict__ x,
                                                float* __restrict__ out) {
    const int wid = threadIdx.x >> 6;
    const int lane = threadIdx.x & 63;
    const int r = blockIdx.x * 4 + wid;
    if (r >= N_NODES) return;
    const int start = row_ptr[r];
    const int end   = row_ptr[r + 1];

    if (D == 128) {
        const float* xb = x + lane * 2;
        float ax0 = 0.f, ay0 = 0.f, ax1 = 0.f, ay1 = 0.f;
        int e = start;
        for (; e + 1 < end; e += 2) {
            int2 e0 = csr[e], e1 = csr[e + 1];
            float v0 = __int_as_float(e0.y), v1 = __int_as_float(e1.y);
            float2 x0 = *reinterpret_cast<const float2*>(xb + (size_t)e0.x * 128);
            float2 x1 = *reinterpret_cast<const float2*>(xb + (size_t)e1.x * 128);
            ax0 = fmaf(v0, x0.x, ax0); ay0 = fmaf(v0, x0.y, ay0);
            ax1 = fmaf(v1, x1.x, ax1); ay1 = fmaf(v1, x1.y, ay1);
        }
        if (e < end) {
            int2 e0 = csr[e];
            float v0 = __int_as_float(e0.y);
            float2 x0 = *reinterpret_cast<const float2*>(xb + (size_t)e0.x * 128);
            ax0 = fmaf(v0, x0.x, ax0); ay0 = fmaf(v0, x0.y, ay0);
        }
        float rx = ax0 + ax1, ry = ay0 + ay1;
        if (RELU) { rx = fmaxf(rx, 0.f); ry = fmaxf(ry, 0.f); }
        float2 res = {rx, ry};
        *reinterpret_cast<float2*>(out + (size_t)r * 128 + lane * 2) = res;
    } else {  // D == 64
        const float* xb = x + lane;
        float a0 = 0.f, a1 = 0.f;
        int e = start;
        for (; e + 1 < end; e += 2) {
            int2 e0 = csr[e], e1 = csr[e + 1];
            a0 = fmaf(__int_as_float(e0.y), xb[(size_t)e0.x * 64], a0);
            a1 = fmaf(__int_as_float(e1.y), xb[(size_t)e1.x * 64], a1);
        }
        if (e < end) a0 = fmaf(__int_as_float(csr[e].y), xb[(size_t)csr[e].x * 64], a0);
        float res = a0 + a1;
        if (RELU) res = fmaxf(res, 0.f);
        out[(size_t)r * 64 + lane] = res;
    }
}

// ---------------- launch ----------------

extern "C" void kernel_launch(void* const* d_in, const int* in_sizes, int n_in,
                              void* d_out, int out_size, void* d_ws, size_t ws_size,
                              hipStream_t stream) {
    const float* x    = (const float*)d_in[0];
    const int*   row  = (const int*)  d_in[1];
    const int*   col  = (const int*)  d_in[2];
    const float* vals = (const float*)d_in[3];
    const float* W1   = (const float*)d_in[4];
    const float* W2   = (const float*)d_in[5];
    float* out = (float*)d_out;

    // workspace layout (256B-aligned chunks)
    char* ws = (char*)d_ws;
    auto align = [](size_t v) { return (v + 255) & ~(size_t)255; };
    int*   counts  = (int*)ws;                 ws += align(sizeof(int) * N_NODES);
    int*   row_ptr = (int*)ws;                 ws += align(sizeof(int) * (N_NODES + 1));
    int*   cursor  = (int*)ws;                 ws += align(sizeof(int) * N_NODES);
    int*   bsum    = (int*)ws;                 ws += align(sizeof(int) * SCAN_BLOCKS);
    int*   boff    = (int*)ws;                 ws += align(sizeof(int) * SCAN_BLOCKS);
    int2*  csr     = (int2*)ws;                ws += align(sizeof(int2) * N_EDGES);
    float* tbuf    = (float*)ws;               ws += align(sizeof(float) * N_NODES * HID_DIM);
    float* hbuf    = (float*)ws;               ws += align(sizeof(float) * N_NODES * HID_DIM);

    // ---- CSR build (used by both layers) ----
    zero_ints<<<196, 256, 0, stream>>>(counts, N_NODES);
    hist_rows<<<1024, 256, 0, stream>>>(row, counts);
    scan_part<<<SCAN_BLOCKS, SCAN_THREADS, 0, stream>>>(counts, bsum);
    scan_bsum<<<1, 64, 0, stream>>>(bsum, boff);
    scan_final<<<SCAN_BLOCKS, SCAN_THREADS, 0, stream>>>(counts, boff, row_ptr, cursor);
    scatter_csr<<<1024, 256, 0, stream>>>(row, col, vals, cursor, csr);

    // ---- layer 1: h = relu( A @ (x @ W1) ) ----
    gemm_tile<HID_DIM><<<dim3((N_NODES + 63) / 64, HID_DIM / 64), 256, 0, stream>>>(x, W1, tbuf, N_NODES);
    spmm_csr<HID_DIM, true><<<(N_NODES + 3) / 4, 256, 0, stream>>>(row_ptr, csr, tbuf, hbuf);

    // ---- layer 2: out = A @ (h @ W2) ----
    gemm_tile<OUT_DIM><<<dim3((N_NODES + 63) / 64, OUT_DIM / 64), 256, 0, stream>>>(hbuf, W2, tbuf, N_NODES);
    spmm_csr<OUT_DIM, false><<<(N_NODES + 3) / 4, 256, 0, stream>>>(row_ptr, csr, tbuf, out);
}

// Round 5
// 276.227 us; speedup vs baseline: 10.7654x; 1.0053x over previous
//
#include <hip/hip_runtime.h>

#define N_NODES 50000
#define N_EDGES 800000
#define IN_DIM 128
#define HID_DIM 128
#define OUT_DIM 64

#define SCAN_BLOCKS 64
#define SCAN_THREADS 256
#define SCAN_CH 4        // 64*256*4 = 65536 >= N_NODES

#define ROWS_PER_PASS 8192
#define N_PASSES 7               // ceil(50000/8192)
#define SCAT_BLOCKS_PER_PASS 512

// ---------------- CSR build ----------------

__global__ void zero_ints(int* __restrict__ p, int n) {
    int i = blockIdx.x * blockDim.x + threadIdx.x;
    int stride = gridDim.x * blockDim.x;
    for (; i < n; i += stride) p[i] = 0;
}

__global__ void hist_rows(const int* __restrict__ row, int* __restrict__ counts) {
    int e = blockIdx.x * blockDim.x + threadIdx.x;
    int stride = gridDim.x * blockDim.x;
    for (; e < N_EDGES; e += stride) atomicAdd(&counts[row[e]], 1);
}

// scan stage 1: per-block partial sums of counts
__global__ __launch_bounds__(SCAN_THREADS) void scan_part(const int* __restrict__ counts,
                                                          int* __restrict__ bsum) {
    __shared__ int red[SCAN_THREADS];
    const int b = blockIdx.x, t = threadIdx.x;
    const int base = (b * SCAN_THREADS + t) * SCAN_CH;
    int s = 0;
#pragma unroll
    for (int i = 0; i < SCAN_CH; ++i) {
        int idx = base + i;
        if (idx < N_NODES) s += counts[idx];
    }
    red[t] = s;
    __syncthreads();
#pragma unroll
    for (int off = SCAN_THREADS / 2; off > 0; off >>= 1) {
        if (t < off) red[t] += red[t + off];
        __syncthreads();
    }
    if (t == 0) bsum[b] = red[0];
}

// scan stage 2: one-wave exclusive scan of the 64 block sums
__global__ void scan_bsum(const int* __restrict__ bsum, int* __restrict__ boff) {
    const int t = threadIdx.x;     // 0..63
    int orig = bsum[t];
    int v = orig;
#pragma unroll
    for (int off = 1; off < 64; off <<= 1) {
        int u = __shfl_up(v, off, 64);
        if (t >= off) v += u;
    }
    boff[t] = v - orig;            // exclusive prefix
}

// scan stage 3: per-block rescan + write row_ptr / cursor
__global__ __launch_bounds__(SCAN_THREADS) void scan_final(const int* __restrict__ counts,
                                                           const int* __restrict__ boff,
                                                           int* __restrict__ row_ptr,
                                                           int* __restrict__ cursor) {
    __shared__ int sums[SCAN_THREADS];
    const int b = blockIdx.x, t = threadIdx.x;
    const int base = (b * SCAN_THREADS + t) * SCAN_CH;
    int local[SCAN_CH];
    int s = 0;
#pragma unroll
    for (int i = 0; i < SCAN_CH; ++i) {
        int idx = base + i;
        int c = (idx < N_NODES) ? counts[idx] : 0;
        local[i] = c;
        s += c;
    }
    sums[t] = s;
    __syncthreads();
#pragma unroll
    for (int off = 1; off < SCAN_THREADS; off <<= 1) {
        int v = sums[t];
        int add = (t >= off) ? sums[t - off] : 0;
        __syncthreads();
        sums[t] = v + add;
        __syncthreads();
    }
    int run = boff[b] + sums[t] - s;   // global exclusive prefix for this thread's chunk
#pragma unroll
    for (int i = 0; i < SCAN_CH; ++i) {
        int idx = base + i;
        if (idx < N_NODES) {
            row_ptr[idx] = run;
            cursor[idx]  = run;
            run += local[i];
        }
    }
    if (b == 0 && t == 0) row_ptr[N_NODES] = N_EDGES;
}

// scatter edges into packed CSR, row-range passes for write locality.
// pass p handles rows [p*8192, (p+1)*8192): dest region ~0.9MB stays hot in L2,
// stores merge into full lines instead of 64B-line-per-8B-store amplification.
__global__ __launch_bounds__(256) void scatter_pass(const int* __restrict__ row,
                                                    const int* __restrict__ col,
                                                    const float* __restrict__ vals,
                                                    int* __restrict__ cursor,
                                                    int2* __restrict__ csr) {
    const int pass = blockIdx.x / SCAT_BLOCKS_PER_PASS;
    const int blk  = blockIdx.x % SCAT_BLOCKS_PER_PASS;
    const int rlo  = pass * ROWS_PER_PASS;
    int e = blk * 256 + threadIdx.x;
    const int stride = SCAT_BLOCKS_PER_PASS * 256;
    for (; e < N_EDGES; e += stride) {
        int r = row[e];
        if ((unsigned)(r - rlo) < (unsigned)ROWS_PER_PASS) {
            int p = atomicAdd(&cursor[r], 1);
            csr[p] = make_int2(col[e], __float_as_int(vals[e]));
        }
    }
}

// ---------------- dense GEMM: out[M,N] = A[M,128] @ W[128,N] ----------------
// BM=64, BN=64, K=128 full. A transposed into LDS, W tile k-major in LDS.
// 256 threads as 16x16, each computes a 4x4 micro-tile. 64 KB LDS -> 2 blocks/CU.

template<int N>
__global__ __launch_bounds__(256) void gemm_tile(const float* __restrict__ A,
                                                 const float* __restrict__ W,
                                                 float* __restrict__ out, int M) {
    __shared__ float At[128][64];   // At[k][m]
    __shared__ float Wt[128][64];   // Wt[k][n]
    const int tid = threadIdx.x;
    const int r0  = blockIdx.x * 64;
    const int bn0 = blockIdx.y * 64;

    // stage W tile: 128 rows x 16 float4, coalesced read, contiguous LDS write
#pragma unroll
    for (int it = 0; it < 8; ++it) {
        int f4 = tid + it * 256;          // 0..2047
        int k = f4 >> 4, c = f4 & 15;
        float4 w = *reinterpret_cast<const float4*>(&W[(size_t)k * N + bn0 + c * 4]);
        *reinterpret_cast<float4*>(&Wt[k][c * 4]) = w;
    }

    // stage A tile transposed: lane = row, wave = k-quarter
    {
        const int m  = tid & 63;
        const int kq = tid >> 6;          // 0..3
        const int r  = r0 + m;
        const bool valid = r < M;
        const float* Ar = A + (size_t)r * 128 + kq * 32;
#pragma unroll
        for (int it = 0; it < 8; ++it) {
            float4 a = {0.f, 0.f, 0.f, 0.f};
            if (valid) a = *reinterpret_cast<const float4*>(&Ar[it * 4]);
            int k = kq * 32 + it * 4;
            At[k + 0][m] = a.x;
            At[k + 1][m] = a.y;
            At[k + 2][m] = a.z;
            At[k + 3][m] = a.w;
        }
    }
    __syncthreads();

    const int tx = tid & 15;              // n group
    const int ty = tid >> 4;              // m group
    float acc[4][4];
#pragma unroll
    for (int i = 0; i < 4; ++i)
#pragma unroll
        for (int j = 0; j < 4; ++j) acc[i][j] = 0.f;

#pragma unroll 4
    for (int k = 0; k < 128; ++k) {
        float4 a = *reinterpret_cast<const float4*>(&At[k][ty * 4]);
        float4 w = *reinterpret_cast<const float4*>(&Wt[k][tx * 4]);
        acc[0][0] = fmaf(a.x, w.x, acc[0][0]); acc[0][1] = fmaf(a.x, w.y, acc[0][1]);
        acc[0][2] = fmaf(a.x, w.z, acc[0][2]); acc[0][3] = fmaf(a.x, w.w, acc[0][3]);
        acc[1][0] = fmaf(a.y, w.x, acc[1][0]); acc[1][1] = fmaf(a.y, w.y, acc[1][1]);
        acc[1][2] = fmaf(a.y, w.z, acc[1][2]); acc[1][3] = fmaf(a.y, w.w, acc[1][3]);
        acc[2][0] = fmaf(a.z, w.x, acc[2][0]); acc[2][1] = fmaf(a.z, w.y, acc[2][1]);
        acc[2][2] = fmaf(a.z, w.z, acc[2][2]); acc[2][3] = fmaf(a.z, w.w, acc[2][3]);
        acc[3][0] = fmaf(a.w, w.x, acc[3][0]); acc[3][1] = fmaf(a.w, w.y, acc[3][1]);
        acc[3][2] = fmaf(a.w, w.z, acc[3][2]); acc[3][3] = fmaf(a.w, w.w, acc[3][3]);
    }

#pragma unroll
    for (int i = 0; i < 4; ++i) {
        int r = r0 + ty * 4 + i;
        if (r < M) {
            float4 v = {acc[i][0], acc[i][1], acc[i][2], acc[i][3]};
            *reinterpret_cast<float4*>(&out[(size_t)r * N + bn0 + tx * 4]) = v;
        }
    }
}

// ---------------- CSR SPMM: out[r,:] = (relu?) sum_e val[e] * x[col[e],:], 1 wave/row ----------------

template<int D, bool RELU>
__global__ __launch_bounds__(256) void spmm_csr(const int* __restrict__ row_ptr,
                                                const int2* __restrict__ csr,
                                                const float* __restrict__ x,
                                                float* __restrict__ out) {
    const int wid = threadIdx.x >> 6;
    const int lane = threadIdx.x & 63;
    const int r = blockIdx.x * 4 + wid;
    if (r >= N_NODES) return;
    const int start = row_ptr[r];
    const int end   = row_ptr[r + 1];

    if (D == 128) {
        const float* xb = x + lane * 2;
        float ax0 = 0.f, ay0 = 0.f, ax1 = 0.f, ay1 = 0.f;
        int e = start;
        for (; e + 1 < end; e += 2) {
            int2 e0 = csr[e], e1 = csr[e + 1];
            float v0 = __int_as_float(e0.y), v1 = __int_as_float(e1.y);
            float2 x0 = *reinterpret_cast<const float2*>(xb + (size_t)e0.x * 128);
            float2 x1 = *reinterpret_cast<const float2*>(xb + (size_t)e1.x * 128);
            ax0 = fmaf(v0, x0.x, ax0); ay0 = fmaf(v0, x0.y, ay0);
            ax1 = fmaf(v1, x1.x, ax1); ay1 = fmaf(v1, x1.y, ay1);
        }
        if (e < end) {
            int2 e0 = csr[e];
            float v0 = __int_as_float(e0.y);
            float2 x0 = *reinterpret_cast<const float2*>(xb + (size_t)e0.x * 128);
            ax0 = fmaf(v0, x0.x, ax0); ay0 = fmaf(v0, x0.y, ay0);
        }
        float rx = ax0 + ax1, ry = ay0 + ay1;
        if (RELU) { rx = fmaxf(rx, 0.f); ry = fmaxf(ry, 0.f); }
        float2 res = {rx, ry};
        *reinterpret_cast<float2*>(out + (size_t)r * 128 + lane * 2) = res;
    } else {  // D == 64
        const float* xb = x + lane;
        float a0 = 0.f, a1 = 0.f;
        int e = start;
        for (; e + 1 < end; e += 2) {
            int2 e0 = csr[e], e1 = csr[e + 1];
            a0 = fmaf(__int_as_float(e0.y), xb[(size_t)e0.x * 64], a0);
            a1 = fmaf(__int_as_float(e1.y), xb[(size_t)e1.x * 64], a1);
        }
        if (e < end) a0 = fmaf(__int_as_float(csr[e].y), xb[(size_t)csr[e].x * 64], a0);
        float res = a0 + a1;
        if (RELU) res = fmaxf(res, 0.f);
        out[(size_t)r * 64 + lane] = res;
    }
}

// ---------------- launch ----------------

extern "C" void kernel_launch(void* const* d_in, const int* in_sizes, int n_in,
                              void* d_out, int out_size, void* d_ws, size_t ws_size,
                              hipStream_t stream) {
    const float* x    = (const float*)d_in[0];
    const int*   row  = (const int*)  d_in[1];
    const int*   col  = (const int*)  d_in[2];
    const float* vals = (const float*)d_in[3];
    const float* W1   = (const float*)d_in[4];
    const float* W2   = (const float*)d_in[5];
    float* out = (float*)d_out;

    // workspace layout (256B-aligned chunks)
    char* ws = (char*)d_ws;
    auto align = [](size_t v) { return (v + 255) & ~(size_t)255; };
    int*   counts  = (int*)ws;                 ws += align(sizeof(int) * N_NODES);
    int*   row_ptr = (int*)ws;                 ws += align(sizeof(int) * (N_NODES + 1));
    int*   cursor  = (int*)ws;                 ws += align(sizeof(int) * N_NODES);
    int*   bsum    = (int*)ws;                 ws += align(sizeof(int) * SCAN_BLOCKS);
    int*   boff    = (int*)ws;                 ws += align(sizeof(int) * SCAN_BLOCKS);
    int2*  csr     = (int2*)ws;                ws += align(sizeof(int2) * N_EDGES);
    float* tbuf    = (float*)ws;               ws += align(sizeof(float) * N_NODES * HID_DIM);
    float* hbuf    = (float*)ws;               ws += align(sizeof(float) * N_NODES * HID_DIM);

    // ---- CSR build (used by both layers) ----
    zero_ints<<<196, 256, 0, stream>>>(counts, N_NODES);
    hist_rows<<<1024, 256, 0, stream>>>(row, counts);
    scan_part<<<SCAN_BLOCKS, SCAN_THREADS, 0, stream>>>(counts, bsum);
    scan_bsum<<<1, 64, 0, stream>>>(bsum, boff);
    scan_final<<<SCAN_BLOCKS, SCAN_THREADS, 0, stream>>>(counts, boff, row_ptr, cursor);
    scatter_pass<<<SCAT_BLOCKS_PER_PASS * N_PASSES, 256, 0, stream>>>(row, col, vals, cursor, csr);

    // ---- layer 1: h = relu( A @ (x @ W1) ) ----
    gemm_tile<HID_DIM><<<dim3((N_NODES + 63) / 64, HID_DIM / 64), 256, 0, stream>>>(x, W1, tbuf, N_NODES);
    spmm_csr<HID_DIM, true><<<(N_NODES + 3) / 4, 256, 0, stream>>>(row_ptr, csr, tbuf, hbuf);

    // ---- layer 2: out = A @ (h @ W2) ----
    gemm_tile<OUT_DIM><<<dim3((N_NODES + 63) / 64, OUT_DIM / 64), 256, 0, stream>>>(hbuf, W2, tbuf, N_NODES);
    spmm_csr<OUT_DIM, false><<<(N_NODES + 3) / 4, 256, 0, stream>>>(row_ptr, csr, tbuf, out);
}

// Round 7
// 257.756 us; speedup vs baseline: 11.5368x; 1.0717x over previous
//
#include <hip/hip_runtime.h>
#include <stdint.h>

#define N_NODES 50000
#define N_EDGES 800000
#define IN_DIM 128
#define HID_DIM 128
#define OUT_DIM 64

#define SCAN_BLOCKS 64
#define SCAN_THREADS 256
#define SCAN_CH 4        // 64*256*4 = 65536 >= N_NODES

#define ROWS_PER_PASS 8192
#define N_PASSES 7               // ceil(50000/8192)
#define SCAT_BLOCKS_PER_PASS 512

__device__ __forceinline__ uint32_t pack_bf16x2(float a, float b) {
    uint32_t ba = __float_as_uint(a), bb = __float_as_uint(b);
    ba = (ba + 0x7fffu + ((ba >> 16) & 1u)) >> 16;           // RNE low half
    bb = (bb + 0x7fffu + ((bb >> 16) & 1u)) & 0xffff0000u;   // RNE high half
    return ba | bb;
}

// ---------------- CSR build ----------------

__global__ void zero_ints(int* __restrict__ p, int n) {
    int i = blockIdx.x * blockDim.x + threadIdx.x;
    int stride = gridDim.x * blockDim.x;
    for (; i < n; i += stride) p[i] = 0;
}

__global__ void hist_rows(const int* __restrict__ row, int* __restrict__ counts) {
    int e = blockIdx.x * blockDim.x + threadIdx.x;
    int stride = gridDim.x * blockDim.x;
    for (; e < N_EDGES; e += stride) atomicAdd(&counts[row[e]], 1);
}

__global__ __launch_bounds__(SCAN_THREADS) void scan_part(const int* __restrict__ counts,
                                                          int* __restrict__ bsum) {
    __shared__ int red[SCAN_THREADS];
    const int b = blockIdx.x, t = threadIdx.x;
    const int base = (b * SCAN_THREADS + t) * SCAN_CH;
    int s = 0;
#pragma unroll
    for (int i = 0; i < SCAN_CH; ++i) {
        int idx = base + i;
        if (idx < N_NODES) s += counts[idx];
    }
    red[t] = s;
    __syncthreads();
#pragma unroll
    for (int off = SCAN_THREADS / 2; off > 0; off >>= 1) {
        if (t < off) red[t] += red[t + off];
        __syncthreads();
    }
    if (t == 0) bsum[b] = red[0];
}

__global__ void scan_bsum(const int* __restrict__ bsum, int* __restrict__ boff) {
    const int t = threadIdx.x;     // 0..63
    int orig = bsum[t];
    int v = orig;
#pragma unroll
    for (int off = 1; off < 64; off <<= 1) {
        int u = __shfl_up(v, off, 64);
        if (t >= off) v += u;
    }
    boff[t] = v - orig;            // exclusive prefix
}

__global__ __launch_bounds__(SCAN_THREADS) void scan_final(const int* __restrict__ counts,
                                                           const int* __restrict__ boff,
                                                           int* __restrict__ row_ptr,
                                                           int* __restrict__ cursor) {
    __shared__ int sums[SCAN_THREADS];
    const int b = blockIdx.x, t = threadIdx.x;
    const int base = (b * SCAN_THREADS + t) * SCAN_CH;
    int local[SCAN_CH];
    int s = 0;
#pragma unroll
    for (int i = 0; i < SCAN_CH; ++i) {
        int idx = base + i;
        int c = (idx < N_NODES) ? counts[idx] : 0;
        local[i] = c;
        s += c;
    }
    sums[t] = s;
    __syncthreads();
#pragma unroll
    for (int off = 1; off < SCAN_THREADS; off <<= 1) {
        int v = sums[t];
        int add = (t >= off) ? sums[t - off] : 0;
        __syncthreads();
        sums[t] = v + add;
        __syncthreads();
    }
    int run = boff[b] + sums[t] - s;
#pragma unroll
    for (int i = 0; i < SCAN_CH; ++i) {
        int idx = base + i;
        if (idx < N_NODES) {
            row_ptr[idx] = run;
            cursor[idx]  = run;
            run += local[i];
        }
    }
    if (b == 0 && t == 0) row_ptr[N_NODES] = N_EDGES;
}

// scatter edges into packed CSR, row-range passes for write locality
__global__ __launch_bounds__(256) void scatter_pass(const int* __restrict__ row,
                                                    const int* __restrict__ col,
                                                    const float* __restrict__ vals,
                                                    int* __restrict__ cursor,
                                                    int2* __restrict__ csr) {
    const int pass = blockIdx.x / SCAT_BLOCKS_PER_PASS;
    const int blk  = blockIdx.x % SCAT_BLOCKS_PER_PASS;
    const int rlo  = pass * ROWS_PER_PASS;
    int e = blk * 256 + threadIdx.x;
    const int stride = SCAT_BLOCKS_PER_PASS * 256;
    for (; e < N_EDGES; e += stride) {
        int r = row[e];
        if ((unsigned)(r - rlo) < (unsigned)ROWS_PER_PASS) {
            int p = atomicAdd(&cursor[r], 1);
            csr[p] = make_int2(col[e], __float_as_int(vals[e]));
        }
    }
}

// ---------------- dense GEMM: out[M,N] = A[M,128] @ W[128,N], bf16-packed output ----------------
// BM=64, BN=64, K=128 full. 256 threads as 16x16, 4x4 micro-tile each.

template<int N>
__global__ __launch_bounds__(256) void gemm_tile_bf16(const float* __restrict__ A,
                                                      const float* __restrict__ W,
                                                      uint32_t* __restrict__ out, int M) {
    __shared__ float At[128][64];   // At[k][m]
    __shared__ float Wt[128][64];   // Wt[k][n]
    const int tid = threadIdx.x;
    const int r0  = blockIdx.x * 64;
    const int bn0 = blockIdx.y * 64;

#pragma unroll
    for (int it = 0; it < 8; ++it) {
        int f4 = tid + it * 256;
        int k = f4 >> 4, c = f4 & 15;
        float4 w = *reinterpret_cast<const float4*>(&W[(size_t)k * N + bn0 + c * 4]);
        *reinterpret_cast<float4*>(&Wt[k][c * 4]) = w;
    }
    {
        const int m  = tid & 63;
        const int kq = tid >> 6;
        const int r  = r0 + m;
        const bool valid = r < M;
        const float* Ar = A + (size_t)r * 128 + kq * 32;
#pragma unroll
        for (int it = 0; it < 8; ++it) {
            float4 a = {0.f, 0.f, 0.f, 0.f};
            if (valid) a = *reinterpret_cast<const float4*>(&Ar[it * 4]);
            int k = kq * 32 + it * 4;
            At[k + 0][m] = a.x;
            At[k + 1][m] = a.y;
            At[k + 2][m] = a.z;
            At[k + 3][m] = a.w;
        }
    }
    __syncthreads();

    const int tx = tid & 15;
    const int ty = tid >> 4;
    float acc[4][4];
#pragma unroll
    for (int i = 0; i < 4; ++i)
#pragma unroll
        for (int j = 0; j < 4; ++j) acc[i][j] = 0.f;

#pragma unroll 4
    for (int k = 0; k < 128; ++k) {
        float4 a = *reinterpret_cast<const float4*>(&At[k][ty * 4]);
        float4 w = *reinterpret_cast<const float4*>(&Wt[k][tx * 4]);
        acc[0][0] = fmaf(a.x, w.x, acc[0][0]); acc[0][1] = fmaf(a.x, w.y, acc[0][1]);
        acc[0][2] = fmaf(a.x, w.z, acc[0][2]); acc[0][3] = fmaf(a.x, w.w, acc[0][3]);
        acc[1][0] = fmaf(a.y, w.x, acc[1][0]); acc[1][1] = fmaf(a.y, w.y, acc[1][1]);
        acc[1][2] = fmaf(a.y, w.z, acc[1][2]); acc[1][3] = fmaf(a.y, w.w, acc[1][3]);
        acc[2][0] = fmaf(a.z, w.x, acc[2][0]); acc[2][1] = fmaf(a.z, w.y, acc[2][1]);
        acc[2][2] = fmaf(a.z, w.z, acc[2][2]); acc[2][3] = fmaf(a.z, w.w, acc[2][3]);
        acc[3][0] = fmaf(a.w, w.x, acc[3][0]); acc[3][1] = fmaf(a.w, w.y, acc[3][1]);
        acc[3][2] = fmaf(a.w, w.z, acc[3][2]); acc[3][3] = fmaf(a.w, w.w, acc[3][3]);
    }

#pragma unroll
    for (int i = 0; i < 4; ++i) {
        int r = r0 + ty * 4 + i;
        if (r < M) {
            uint2 p = { pack_bf16x2(acc[i][0], acc[i][1]),
                        pack_bf16x2(acc[i][2], acc[i][3]) };
            // packed word index: (bn0 + tx*4)/2  — bn0/2 offset was the R5 bug
            *reinterpret_cast<uint2*>(&out[(size_t)r * (N / 2) + bn0 / 2 + tx * 2]) = p;
        }
    }
}

// ---------------- CSR SPMM over bf16-packed operand, f32 accumulate ----------------

// D=128: operand xp is [N][64] packed bf16x2; lane handles dims {2*lane, 2*lane+1}
template<bool RELU>
__global__ __launch_bounds__(256) void spmm_bf16_128(const int* __restrict__ row_ptr,
                                                     const int2* __restrict__ csr,
                                                     const uint32_t* __restrict__ xp,
                                                     float* __restrict__ out) {
    const int wid = threadIdx.x >> 6;
    const int lane = threadIdx.x & 63;
    const int r = blockIdx.x * 4 + wid;
    if (r >= N_NODES) return;
    const int start = row_ptr[r];
    const int end   = row_ptr[r + 1];
    const uint32_t* xb = xp + lane;

    float alo0 = 0.f, ahi0 = 0.f, alo1 = 0.f, ahi1 = 0.f;
    int e = start;
    for (; e + 1 < end; e += 2) {
        int2 e0 = csr[e], e1 = csr[e + 1];
        float v0 = __int_as_float(e0.y), v1 = __int_as_float(e1.y);
        uint32_t u0 = xb[(size_t)e0.x * 64];
        uint32_t u1 = xb[(size_t)e1.x * 64];
        alo0 = fmaf(v0, __uint_as_float(u0 << 16), alo0);
        ahi0 = fmaf(v0, __uint_as_float(u0 & 0xffff0000u), ahi0);
        alo1 = fmaf(v1, __uint_as_float(u1 << 16), alo1);
        ahi1 = fmaf(v1, __uint_as_float(u1 & 0xffff0000u), ahi1);
    }
    if (e < end) {
        int2 e0 = csr[e];
        float v0 = __int_as_float(e0.y);
        uint32_t u0 = xb[(size_t)e0.x * 64];
        alo0 = fmaf(v0, __uint_as_float(u0 << 16), alo0);
        ahi0 = fmaf(v0, __uint_as_float(u0 & 0xffff0000u), ahi0);
    }
    float rlo = alo0 + alo1, rhi = ahi0 + ahi1;
    if (RELU) { rlo = fmaxf(rlo, 0.f); rhi = fmaxf(rhi, 0.f); }
    float2 res = {rlo, rhi};
    *reinterpret_cast<float2*>(out + (size_t)r * 128 + lane * 2) = res;
}

// D=64: operand xp is [N][32] packed bf16x2; half-wave per edge, 2 edges/iter
__global__ __launch_bounds__(256) void spmm_bf16_64(const int* __restrict__ row_ptr,
                                                    const int2* __restrict__ csr,
                                                    const uint32_t* __restrict__ xp,
                                                    float* __restrict__ out) {
    const int wid = threadIdx.x >> 6;
    const int lane = threadIdx.x & 63;
    const int r = blockIdx.x * 4 + wid;
    if (r >= N_NODES) return;
    const int start = row_ptr[r];
    const int end   = row_ptr[r + 1];
    const int j = lane & 31;
    const int half = lane >> 5;
    const uint32_t* xb = xp + j;

    float alo = 0.f, ahi = 0.f;
    for (int e = start + half; e < end; e += 2) {
        int2 ed = csr[e];
        float v = __int_as_float(ed.y);
        uint32_t u = xb[(size_t)ed.x * 32];
        alo = fmaf(v, __uint_as_float(u << 16), alo);
        ahi = fmaf(v, __uint_as_float(u & 0xffff0000u), ahi);
    }
    alo += __shfl_xor(alo, 32);
    ahi += __shfl_xor(ahi, 32);
    if (half == 0) {
        float2 res = {alo, ahi};
        *reinterpret_cast<float2*>(out + (size_t)r * 64 + j * 2) = res;
    }
}

// ---------------- launch ----------------

extern "C" void kernel_launch(void* const* d_in, const int* in_sizes, int n_in,
                              void* d_out, int out_size, void* d_ws, size_t ws_size,
                              hipStream_t stream) {
    const float* x    = (const float*)d_in[0];
    const int*   row  = (const int*)  d_in[1];
    const int*   col  = (const int*)  d_in[2];
    const float* vals = (const float*)d_in[3];
    const float* W1   = (const float*)d_in[4];
    const float* W2   = (const float*)d_in[5];
    float* out = (float*)d_out;

    // workspace layout (256B-aligned chunks)
    char* ws = (char*)d_ws;
    auto align = [](size_t v) { return (v + 255) & ~(size_t)255; };
    int*      counts  = (int*)ws;              ws += align(sizeof(int) * N_NODES);
    int*      row_ptr = (int*)ws;              ws += align(sizeof(int) * (N_NODES + 1));
    int*      cursor  = (int*)ws;              ws += align(sizeof(int) * N_NODES);
    int*      bsum    = (int*)ws;              ws += align(sizeof(int) * SCAN_BLOCKS);
    int*      boff    = (int*)ws;              ws += align(sizeof(int) * SCAN_BLOCKS);
    int2*     csr     = (int2*)ws;             ws += align(sizeof(int2) * N_EDGES);
    uint32_t* tpk     = (uint32_t*)ws;         ws += align(sizeof(uint32_t) * N_NODES * 64);  // t1 (64) or t2 (32) packed
    float*    hbuf    = (float*)ws;            ws += align(sizeof(float) * N_NODES * HID_DIM);

    // ---- CSR build (used by both layers) ----
    zero_ints<<<196, 256, 0, stream>>>(counts, N_NODES);
    hist_rows<<<1024, 256, 0, stream>>>(row, counts);
    scan_part<<<SCAN_BLOCKS, SCAN_THREADS, 0, stream>>>(counts, bsum);
    scan_bsum<<<1, 64, 0, stream>>>(bsum, boff);
    scan_final<<<SCAN_BLOCKS, SCAN_THREADS, 0, stream>>>(counts, boff, row_ptr, cursor);
    scatter_pass<<<SCAT_BLOCKS_PER_PASS * N_PASSES, 256, 0, stream>>>(row, col, vals, cursor, csr);

    // ---- layer 1: t1 = bf16(x @ W1); h = relu( A @ t1 ) ----
    gemm_tile_bf16<HID_DIM><<<dim3((N_NODES + 63) / 64, HID_DIM / 64), 256, 0, stream>>>(x, W1, tpk, N_NODES);
    spmm_bf16_128<true><<<(N_NODES + 3) / 4, 256, 0, stream>>>(row_ptr, csr, tpk, hbuf);

    // ---- layer 2: t2 = bf16(h @ W2); out = A @ t2 ----
    gemm_tile_bf16<OUT_DIM><<<dim3((N_NODES + 63) / 64, OUT_DIM / 64), 256, 0, stream>>>(hbuf, W2, tpk, N_NODES);
    spmm_bf16_64<<<(N_NODES + 3) / 4, 256, 0, stream>>>(row_ptr, csr, tpk, out);
}

// Round 8
// 218.366 us; speedup vs baseline: 13.6179x; 1.1804x over previous
//
#include <hip/hip_runtime.h>
#include <stdint.h>

#define N_NODES 50000
#define N_EDGES 800000
#define IN_DIM 128
#define HID_DIM 128
#define OUT_DIM 64

#define SCAN_BLOCKS 64
#define SCAN_THREADS 256
#define SCAN_CH 4        // 64*256*4 = 65536 >= N_NODES

#define XCD_GROUPS 8
#define ROWS_PER_XCD (N_NODES / XCD_GROUPS)   // 6250 exactly
#define SCAT_BLOCKS_PER_XCD 128

__device__ __forceinline__ uint32_t pack_bf16x2(float a, float b) {
    uint32_t ba = __float_as_uint(a), bb = __float_as_uint(b);
    ba = (ba + 0x7fffu + ((ba >> 16) & 1u)) >> 16;           // RNE low half
    bb = (bb + 0x7fffu + ((bb >> 16) & 1u)) & 0xffff0000u;   // RNE high half
    return ba | bb;
}

// ---------------- CSR build ----------------

__global__ void zero_ints(int* __restrict__ p, int n) {
    int i = blockIdx.x * blockDim.x + threadIdx.x;
    int stride = gridDim.x * blockDim.x;
    for (; i < n; i += stride) p[i] = 0;
}

__global__ void hist_rows(const int* __restrict__ row, int* __restrict__ counts) {
    int e = blockIdx.x * blockDim.x + threadIdx.x;
    int stride = gridDim.x * blockDim.x;
    for (; e < N_EDGES; e += stride) atomicAdd(&counts[row[e]], 1);
}

__global__ __launch_bounds__(SCAN_THREADS) void scan_part(const int* __restrict__ counts,
                                                          int* __restrict__ bsum) {
    __shared__ int red[SCAN_THREADS];
    const int b = blockIdx.x, t = threadIdx.x;
    const int base = (b * SCAN_THREADS + t) * SCAN_CH;
    int s = 0;
#pragma unroll
    for (int i = 0; i < SCAN_CH; ++i) {
        int idx = base + i;
        if (idx < N_NODES) s += counts[idx];
    }
    red[t] = s;
    __syncthreads();
#pragma unroll
    for (int off = SCAN_THREADS / 2; off > 0; off >>= 1) {
        if (t < off) red[t] += red[t + off];
        __syncthreads();
    }
    if (t == 0) bsum[b] = red[0];
}

__global__ void scan_bsum(const int* __restrict__ bsum, int* __restrict__ boff) {
    const int t = threadIdx.x;     // 0..63
    int orig = bsum[t];
    int v = orig;
#pragma unroll
    for (int off = 1; off < 64; off <<= 1) {
        int u = __shfl_up(v, off, 64);
        if (t >= off) v += u;
    }
    boff[t] = v - orig;            // exclusive prefix
}

__global__ __launch_bounds__(SCAN_THREADS) void scan_final(const int* __restrict__ counts,
                                                           const int* __restrict__ boff,
                                                           int* __restrict__ row_ptr,
                                                           int* __restrict__ cursor) {
    __shared__ int sums[SCAN_THREADS];
    const int b = blockIdx.x, t = threadIdx.x;
    const int base = (b * SCAN_THREADS + t) * SCAN_CH;
    int local[SCAN_CH];
    int s = 0;
#pragma unroll
    for (int i = 0; i < SCAN_CH; ++i) {
        int idx = base + i;
        int c = (idx < N_NODES) ? counts[idx] : 0;
        local[i] = c;
        s += c;
    }
    sums[t] = s;
    __syncthreads();
#pragma unroll
    for (int off = 1; off < SCAN_THREADS; off <<= 1) {
        int v = sums[t];
        int add = (t >= off) ? sums[t - off] : 0;
        __syncthreads();
        sums[t] = v + add;
        __syncthreads();
    }
    int run = boff[b] + sums[t] - s;
#pragma unroll
    for (int i = 0; i < SCAN_CH; ++i) {
        int idx = base + i;
        if (idx < N_NODES) {
            row_ptr[idx] = run;
            cursor[idx]  = run;
            run += local[i];
        }
    }
    if (b == 0 && t == 0) row_ptr[N_NODES] = N_EDGES;
}

// scatter edges into packed CSR, XCD-partitioned destinations:
// blocks with the same (blockIdx & 7) land on the same XCD (round-robin dispatch);
// group g owns rows [g*6250, (g+1)*6250) so its ~0.8MB dest region is written by
// exactly one XCD's L2 -> lines fill completely before writeback.
__global__ __launch_bounds__(256) void scatter_xcd(const int* __restrict__ row,
                                                   const int* __restrict__ col,
                                                   const float* __restrict__ vals,
                                                   int* __restrict__ cursor,
                                                   int2* __restrict__ csr) {
    const int xcd = blockIdx.x & (XCD_GROUPS - 1);
    const int blk = blockIdx.x >> 3;
    const int rlo = xcd * ROWS_PER_XCD;
    int e = blk * 256 + threadIdx.x;
    const int stride = SCAT_BLOCKS_PER_XCD * 256;
    for (; e < N_EDGES; e += stride) {
        int r = row[e];
        if ((unsigned)(r - rlo) < (unsigned)ROWS_PER_XCD) {
            int p = atomicAdd(&cursor[r], 1);
            csr[p] = make_int2(col[e], __float_as_int(vals[e]));
        }
    }
}

// ---------------- dense GEMM: out[M,N] = A[M,128] @ W[128,N], bf16-packed output ----------------

template<int N>
__global__ __launch_bounds__(256) void gemm_tile_bf16(const float* __restrict__ A,
                                                      const float* __restrict__ W,
                                                      uint32_t* __restrict__ out, int M) {
    __shared__ float At[128][64];   // At[k][m]
    __shared__ float Wt[128][64];   // Wt[k][n]
    const int tid = threadIdx.x;
    const int r0  = blockIdx.x * 64;
    const int bn0 = blockIdx.y * 64;

#pragma unroll
    for (int it = 0; it < 8; ++it) {
        int f4 = tid + it * 256;
        int k = f4 >> 4, c = f4 & 15;
        float4 w = *reinterpret_cast<const float4*>(&W[(size_t)k * N + bn0 + c * 4]);
        *reinterpret_cast<float4*>(&Wt[k][c * 4]) = w;
    }
    {
        const int m  = tid & 63;
        const int kq = tid >> 6;
        const int r  = r0 + m;
        const bool valid = r < M;
        const float* Ar = A + (size_t)r * 128 + kq * 32;
#pragma unroll
        for (int it = 0; it < 8; ++it) {
            float4 a = {0.f, 0.f, 0.f, 0.f};
            if (valid) a = *reinterpret_cast<const float4*>(&Ar[it * 4]);
            int k = kq * 32 + it * 4;
            At[k + 0][m] = a.x;
            At[k + 1][m] = a.y;
            At[k + 2][m] = a.z;
            At[k + 3][m] = a.w;
        }
    }
    __syncthreads();

    const int tx = tid & 15;
    const int ty = tid >> 4;
    float acc[4][4];
#pragma unroll
    for (int i = 0; i < 4; ++i)
#pragma unroll
        for (int j = 0; j < 4; ++j) acc[i][j] = 0.f;

#pragma unroll 4
    for (int k = 0; k < 128; ++k) {
        float4 a = *reinterpret_cast<const float4*>(&At[k][ty * 4]);
        float4 w = *reinterpret_cast<const float4*>(&Wt[k][tx * 4]);
        acc[0][0] = fmaf(a.x, w.x, acc[0][0]); acc[0][1] = fmaf(a.x, w.y, acc[0][1]);
        acc[0][2] = fmaf(a.x, w.z, acc[0][2]); acc[0][3] = fmaf(a.x, w.w, acc[0][3]);
        acc[1][0] = fmaf(a.y, w.x, acc[1][0]); acc[1][1] = fmaf(a.y, w.y, acc[1][1]);
        acc[1][2] = fmaf(a.y, w.z, acc[1][2]); acc[1][3] = fmaf(a.y, w.w, acc[1][3]);
        acc[2][0] = fmaf(a.z, w.x, acc[2][0]); acc[2][1] = fmaf(a.z, w.y, acc[2][1]);
        acc[2][2] = fmaf(a.z, w.z, acc[2][2]); acc[2][3] = fmaf(a.z, w.w, acc[2][3]);
        acc[3][0] = fmaf(a.w, w.x, acc[3][0]); acc[3][1] = fmaf(a.w, w.y, acc[3][1]);
        acc[3][2] = fmaf(a.w, w.z, acc[3][2]); acc[3][3] = fmaf(a.w, w.w, acc[3][3]);
    }

#pragma unroll
    for (int i = 0; i < 4; ++i) {
        int r = r0 + ty * 4 + i;
        if (r < M) {
            uint2 p = { pack_bf16x2(acc[i][0], acc[i][1]),
                        pack_bf16x2(acc[i][2], acc[i][3]) };
            *reinterpret_cast<uint2*>(&out[(size_t)r * (N / 2) + bn0 / 2 + tx * 2]) = p;
        }
    }
}

// ---------------- CSR SPMM over bf16-packed operand, f32 accumulate ----------------

// D=128: xp is [N][64] packed bf16x2; lane handles dims {2*lane, 2*lane+1}; 4-edge unroll
template<bool RELU>
__global__ __launch_bounds__(256) void spmm_bf16_128(const int* __restrict__ row_ptr,
                                                     const int2* __restrict__ csr,
                                                     const uint32_t* __restrict__ xp,
                                                     float* __restrict__ out) {
    const int wid = threadIdx.x >> 6;
    const int lane = threadIdx.x & 63;
    const int r = blockIdx.x * 4 + wid;
    if (r >= N_NODES) return;
    const int start = row_ptr[r];
    const int end   = row_ptr[r + 1];
    const uint32_t* xb = xp + lane;

    float alo0 = 0.f, ahi0 = 0.f, alo1 = 0.f, ahi1 = 0.f;
    float alo2 = 0.f, ahi2 = 0.f, alo3 = 0.f, ahi3 = 0.f;
    int e = start;
    for (; e + 3 < end; e += 4) {
        int2 e0 = csr[e], e1 = csr[e + 1], e2 = csr[e + 2], e3 = csr[e + 3];
        uint32_t u0 = xb[(size_t)e0.x * 64];
        uint32_t u1 = xb[(size_t)e1.x * 64];
        uint32_t u2 = xb[(size_t)e2.x * 64];
        uint32_t u3 = xb[(size_t)e3.x * 64];
        float v0 = __int_as_float(e0.y), v1 = __int_as_float(e1.y);
        float v2 = __int_as_float(e2.y), v3 = __int_as_float(e3.y);
        alo0 = fmaf(v0, __uint_as_float(u0 << 16), alo0);
        ahi0 = fmaf(v0, __uint_as_float(u0 & 0xffff0000u), ahi0);
        alo1 = fmaf(v1, __uint_as_float(u1 << 16), alo1);
        ahi1 = fmaf(v1, __uint_as_float(u1 & 0xffff0000u), ahi1);
        alo2 = fmaf(v2, __uint_as_float(u2 << 16), alo2);
        ahi2 = fmaf(v2, __uint_as_float(u2 & 0xffff0000u), ahi2);
        alo3 = fmaf(v3, __uint_as_float(u3 << 16), alo3);
        ahi3 = fmaf(v3, __uint_as_float(u3 & 0xffff0000u), ahi3);
    }
    for (; e < end; ++e) {
        int2 e0 = csr[e];
        float v0 = __int_as_float(e0.y);
        uint32_t u0 = xb[(size_t)e0.x * 64];
        alo0 = fmaf(v0, __uint_as_float(u0 << 16), alo0);
        ahi0 = fmaf(v0, __uint_as_float(u0 & 0xffff0000u), ahi0);
    }
    float rlo = (alo0 + alo1) + (alo2 + alo3);
    float rhi = (ahi0 + ahi1) + (ahi2 + ahi3);
    if (RELU) { rlo = fmaxf(rlo, 0.f); rhi = fmaxf(rhi, 0.f); }
    float2 res = {rlo, rhi};
    *reinterpret_cast<float2*>(out + (size_t)r * 128 + lane * 2) = res;
}

// D=64: xp is [N][32] packed bf16x2; half-wave per edge, 2-deep unroll per half
__global__ __launch_bounds__(256) void spmm_bf16_64(const int* __restrict__ row_ptr,
                                                    const int2* __restrict__ csr,
                                                    const uint32_t* __restrict__ xp,
                                                    float* __restrict__ out) {
    const int wid = threadIdx.x >> 6;
    const int lane = threadIdx.x & 63;
    const int r = blockIdx.x * 4 + wid;
    if (r >= N_NODES) return;
    const int start = row_ptr[r];
    const int end   = row_ptr[r + 1];
    const int j = lane & 31;
    const int half = lane >> 5;
    const uint32_t* xb = xp + j;

    float alo0 = 0.f, ahi0 = 0.f, alo1 = 0.f, ahi1 = 0.f;
    int e = start + half;
    for (; e + 2 < end; e += 4) {
        int2 ed0 = csr[e], ed1 = csr[e + 2];
        uint32_t u0 = xb[(size_t)ed0.x * 32];
        uint32_t u1 = xb[(size_t)ed1.x * 32];
        float v0 = __int_as_float(ed0.y), v1 = __int_as_float(ed1.y);
        alo0 = fmaf(v0, __uint_as_float(u0 << 16), alo0);
        ahi0 = fmaf(v0, __uint_as_float(u0 & 0xffff0000u), ahi0);
        alo1 = fmaf(v1, __uint_as_float(u1 << 16), alo1);
        ahi1 = fmaf(v1, __uint_as_float(u1 & 0xffff0000u), ahi1);
    }
    if (e < end) {
        int2 ed = csr[e];
        float v = __int_as_float(ed.y);
        uint32_t u = xb[(size_t)ed.x * 32];
        alo0 = fmaf(v, __uint_as_float(u << 16), alo0);
        ahi0 = fmaf(v, __uint_as_float(u & 0xffff0000u), ahi0);
    }
    float alo = alo0 + alo1, ahi = ahi0 + ahi1;
    alo += __shfl_xor(alo, 32);
    ahi += __shfl_xor(ahi, 32);
    if (half == 0) {
        float2 res = {alo, ahi};
        *reinterpret_cast<float2*>(out + (size_t)r * 64 + j * 2) = res;
    }
}

// ---------------- launch ----------------

extern "C" void kernel_launch(void* const* d_in, const int* in_sizes, int n_in,
                              void* d_out, int out_size, void* d_ws, size_t ws_size,
                              hipStream_t stream) {
    const float* x    = (const float*)d_in[0];
    const int*   row  = (const int*)  d_in[1];
    const int*   col  = (const int*)  d_in[2];
    const float* vals = (const float*)d_in[3];
    const float* W1   = (const float*)d_in[4];
    const float* W2   = (const float*)d_in[5];
    float* out = (float*)d_out;

    // workspace layout (256B-aligned chunks)
    char* ws = (char*)d_ws;
    auto align = [](size_t v) { return (v + 255) & ~(size_t)255; };
    int*      counts  = (int*)ws;              ws += align(sizeof(int) * N_NODES);
    int*      row_ptr = (int*)ws;              ws += align(sizeof(int) * (N_NODES + 1));
    int*      cursor  = (int*)ws;              ws += align(sizeof(int) * N_NODES);
    int*      bsum    = (int*)ws;              ws += align(sizeof(int) * SCAN_BLOCKS);
    int*      boff    = (int*)ws;              ws += align(sizeof(int) * SCAN_BLOCKS);
    int2*     csr     = (int2*)ws;             ws += align(sizeof(int2) * N_EDGES);
    uint32_t* tpk     = (uint32_t*)ws;         ws += align(sizeof(uint32_t) * N_NODES * 64);
    float*    hbuf    = (float*)ws;            ws += align(sizeof(float) * N_NODES * HID_DIM);

    // ---- CSR build (used by both layers) ----
    zero_ints<<<196, 256, 0, stream>>>(counts, N_NODES);
    hist_rows<<<1024, 256, 0, stream>>>(row, counts);
    scan_part<<<SCAN_BLOCKS, SCAN_THREADS, 0, stream>>>(counts, bsum);
    scan_bsum<<<1, 64, 0, stream>>>(bsum, boff);
    scan_final<<<SCAN_BLOCKS, SCAN_THREADS, 0, stream>>>(counts, boff, row_ptr, cursor);
    scatter_xcd<<<SCAT_BLOCKS_PER_XCD * XCD_GROUPS, 256, 0, stream>>>(row, col, vals, cursor, csr);

    // ---- layer 1: t1 = bf16(x @ W1); h = relu( A @ t1 ) ----
    gemm_tile_bf16<HID_DIM><<<dim3((N_NODES + 63) / 64, HID_DIM / 64), 256, 0, stream>>>(x, W1, tpk, N_NODES);
    spmm_bf16_128<true><<<(N_NODES + 3) / 4, 256, 0, stream>>>(row_ptr, csr, tpk, hbuf);

    // ---- layer 2: t2 = bf16(h @ W2); out = A @ t2 ----
    gemm_tile_bf16<OUT_DIM><<<dim3((N_NODES + 63) / 64, OUT_DIM / 64), 256, 0, stream>>>(hbuf, W2, tpk, N_NODES);
    spmm_bf16_64<<<(N_NODES + 3) / 4, 256, 0, stream>>>(row_ptr, csr, tpk, out);
}

// Round 9
// 188.412 us; speedup vs baseline: 15.7829x; 1.1590x over previous
//
#include <hip/hip_runtime.h>
#include <stdint.h>

#define N_NODES 50000
#define N_EDGES 800000
#define IN_DIM 128
#define HID_DIM 128
#define OUT_DIM 64

#define SCAN_BLOCKS 64
#define SCAN_THREADS 256
#define SCAN_CH 4        // 64*256*4 = 65536 >= N_NODES

#define XCD_GROUPS 8
#define ROWS_PER_XCD (N_NODES / XCD_GROUPS)   // 6250 exactly
#define SCAT_BLOCKS_PER_XCD 128

typedef short bf16x8 __attribute__((ext_vector_type(8)));
typedef float f32x4  __attribute__((ext_vector_type(4)));

__device__ __forceinline__ uint32_t pack_bf16x2(float a, float b) {
    uint32_t ba = __float_as_uint(a), bb = __float_as_uint(b);
    ba = (ba + 0x7fffu + ((ba >> 16) & 1u)) >> 16;           // RNE low half
    bb = (bb + 0x7fffu + ((bb >> 16) & 1u)) & 0xffff0000u;   // RNE high half
    return ba | bb;
}

__device__ __forceinline__ unsigned short f2bf(float f) {
    uint32_t u = __float_as_uint(f);
    return (unsigned short)((u + 0x7fffu + ((u >> 16) & 1u)) >> 16);
}

// ---------------- CSR build ----------------

__global__ void zero_ints(int* __restrict__ p, int n) {
    int i = blockIdx.x * blockDim.x + threadIdx.x;
    int stride = gridDim.x * blockDim.x;
    for (; i < n; i += stride) p[i] = 0;
}

__global__ void hist_rows(const int* __restrict__ row, int* __restrict__ counts) {
    int e = blockIdx.x * blockDim.x + threadIdx.x;
    int stride = gridDim.x * blockDim.x;
    for (; e < N_EDGES; e += stride) atomicAdd(&counts[row[e]], 1);
}

__global__ __launch_bounds__(SCAN_THREADS) void scan_part(const int* __restrict__ counts,
                                                          int* __restrict__ bsum) {
    __shared__ int red[SCAN_THREADS];
    const int b = blockIdx.x, t = threadIdx.x;
    const int base = (b * SCAN_THREADS + t) * SCAN_CH;
    int s = 0;
#pragma unroll
    for (int i = 0; i < SCAN_CH; ++i) {
        int idx = base + i;
        if (idx < N_NODES) s += counts[idx];
    }
    red[t] = s;
    __syncthreads();
#pragma unroll
    for (int off = SCAN_THREADS / 2; off > 0; off >>= 1) {
        if (t < off) red[t] += red[t + off];
        __syncthreads();
    }
    if (t == 0) bsum[b] = red[0];
}

__global__ void scan_bsum(const int* __restrict__ bsum, int* __restrict__ boff) {
    const int t = threadIdx.x;     // 0..63
    int orig = bsum[t];
    int v = orig;
#pragma unroll
    for (int off = 1; off < 64; off <<= 1) {
        int u = __shfl_up(v, off, 64);
        if (t >= off) v += u;
    }
    boff[t] = v - orig;            // exclusive prefix
}

__global__ __launch_bounds__(SCAN_THREADS) void scan_final(const int* __restrict__ counts,
                                                           const int* __restrict__ boff,
                                                           int* __restrict__ row_ptr,
                                                           int* __restrict__ cursor) {
    __shared__ int sums[SCAN_THREADS];
    const int b = blockIdx.x, t = threadIdx.x;
    const int base = (b * SCAN_THREADS + t) * SCAN_CH;
    int local[SCAN_CH];
    int s = 0;
#pragma unroll
    for (int i = 0; i < SCAN_CH; ++i) {
        int idx = base + i;
        int c = (idx < N_NODES) ? counts[idx] : 0;
        local[i] = c;
        s += c;
    }
    sums[t] = s;
    __syncthreads();
#pragma unroll
    for (int off = 1; off < SCAN_THREADS; off <<= 1) {
        int v = sums[t];
        int add = (t >= off) ? sums[t - off] : 0;
        __syncthreads();
        sums[t] = v + add;
        __syncthreads();
    }
    int run = boff[b] + sums[t] - s;
#pragma unroll
    for (int i = 0; i < SCAN_CH; ++i) {
        int idx = base + i;
        if (idx < N_NODES) {
            row_ptr[idx] = run;
            cursor[idx]  = run;
            run += local[i];
        }
    }
    if (b == 0 && t == 0) row_ptr[N_NODES] = N_EDGES;
}

// scatter edges into packed CSR, XCD-partitioned destinations
__global__ __launch_bounds__(256) void scatter_xcd(const int* __restrict__ row,
                                                   const int* __restrict__ col,
                                                   const float* __restrict__ vals,
                                                   int* __restrict__ cursor,
                                                   int2* __restrict__ csr) {
    const int xcd = blockIdx.x & (XCD_GROUPS - 1);
    const int blk = blockIdx.x >> 3;
    const int rlo = xcd * ROWS_PER_XCD;
    int e = blk * 256 + threadIdx.x;
    const int stride = SCAT_BLOCKS_PER_XCD * 256;
    for (; e < N_EDGES; e += stride) {
        int r = row[e];
        if ((unsigned)(r - rlo) < (unsigned)ROWS_PER_XCD) {
            int p = atomicAdd(&cursor[r], 1);
            csr[p] = make_int2(col[e], __float_as_int(vals[e]));
        }
    }
}

// ---------------- W -> Wt bf16 transpose-convert: Wt[n][k] = bf16(W[k][n]) ----------------

template<int K, int N>
__global__ void convert_wt(const float* __restrict__ W, unsigned short* __restrict__ Wt) {
    int i = blockIdx.x * blockDim.x + threadIdx.x;   // over N*K
    if (i >= N * K) return;
    int n = i / K, k = i % K;
    Wt[i] = f2bf(W[k * N + n]);
}

// ---------------- MFMA GEMM: outb[M,N](bf16) = A[M,128] @ W[128,N] ----------------
// Per-wave: 16 B-frags (n-half 64 cols x K=128) loop-invariant in VGPRs; stream
// 16-row m-tiles. 16x16x32 bf16 MFMA, verified layouts:
//   A: row=lane&15, k=(lane>>4)*8+j (contiguous 8 -> one b128 load)
//   B (from Wt[n][k] = W^T): col=lane&15, k=(lane>>4)*8+j (same b128 pattern)
//   D: col=lane&15, row=(lane>>4)*4+reg
// 50000 rows = 3125 m-tiles exactly (no tail).

template<int N, bool AF32>
__global__ __launch_bounds__(256) void gemm_mfma(const float* __restrict__ Af,
                                                 const uint32_t* __restrict__ Apk,
                                                 const unsigned short* __restrict__ Wt,
                                                 unsigned short* __restrict__ outb) {
    const int tid = threadIdx.x;
    const int wid = tid >> 6, lane = tid & 63;
    const int l15 = lane & 15, lk = lane >> 4;
    const int n0 = blockIdx.y * 64;

    bf16x8 bfrag[4][4];
#pragma unroll
    for (int t = 0; t < 4; ++t) {
        const unsigned short* wp = Wt + (size_t)(n0 + t * 16 + l15) * 128 + lk * 8;
#pragma unroll
        for (int s = 0; s < 4; ++s)
            bfrag[t][s] = *reinterpret_cast<const bf16x8*>(wp + s * 32);
    }

    for (int mt = blockIdx.x * 4 + wid; mt < 3125; mt += 784) {
        const int row = mt * 16 + l15;
        bf16x8 afrag[4];
        if (AF32) {
            const float* ap = Af + (size_t)row * 128 + lk * 8;
#pragma unroll
            for (int s = 0; s < 4; ++s) {
                float4 p0 = *reinterpret_cast<const float4*>(ap + s * 32);
                float4 p1 = *reinterpret_cast<const float4*>(ap + s * 32 + 4);
                bf16x8 f;
                f[0] = (short)f2bf(p0.x); f[1] = (short)f2bf(p0.y);
                f[2] = (short)f2bf(p0.z); f[3] = (short)f2bf(p0.w);
                f[4] = (short)f2bf(p1.x); f[5] = (short)f2bf(p1.y);
                f[6] = (short)f2bf(p1.z); f[7] = (short)f2bf(p1.w);
                afrag[s] = f;
            }
        } else {
            const uint32_t* ap = Apk + (size_t)row * 64 + lk * 4;
#pragma unroll
            for (int s = 0; s < 4; ++s)
                afrag[s] = *reinterpret_cast<const bf16x8*>(ap + s * 16);
        }

        f32x4 acc[4] = {{0.f,0.f,0.f,0.f},{0.f,0.f,0.f,0.f},{0.f,0.f,0.f,0.f},{0.f,0.f,0.f,0.f}};
#pragma unroll
        for (int s = 0; s < 4; ++s)
#pragma unroll
            for (int t = 0; t < 4; ++t)
                acc[t] = __builtin_amdgcn_mfma_f32_16x16x32_bf16(afrag[s], bfrag[t][s], acc[t], 0, 0, 0);

#pragma unroll
        for (int t = 0; t < 4; ++t)
#pragma unroll
            for (int q = 0; q < 4; ++q) {
                int r = mt * 16 + lk * 4 + q;
                outb[(size_t)r * N + n0 + t * 16 + l15] = f2bf(acc[t][q]);
            }
    }
}

// ---------------- CSR SPMM over bf16-packed operand, f32 accumulate ----------------

// D=128: xp is [N][64] packed bf16x2; lane handles dims {2*lane, 2*lane+1}; 4-edge unroll.
// Output: packed bf16 (feeds gemm2).
template<bool RELU>
__global__ __launch_bounds__(256) void spmm_bf16_128(const int* __restrict__ row_ptr,
                                                     const int2* __restrict__ csr,
                                                     const uint32_t* __restrict__ xp,
                                                     uint32_t* __restrict__ outp) {
    const int wid = threadIdx.x >> 6;
    const int lane = threadIdx.x & 63;
    const int r = blockIdx.x * 4 + wid;
    if (r >= N_NODES) return;
    const int start = row_ptr[r];
    const int end   = row_ptr[r + 1];
    const uint32_t* xb = xp + lane;

    float alo0 = 0.f, ahi0 = 0.f, alo1 = 0.f, ahi1 = 0.f;
    float alo2 = 0.f, ahi2 = 0.f, alo3 = 0.f, ahi3 = 0.f;
    int e = start;
    for (; e + 3 < end; e += 4) {
        int2 e0 = csr[e], e1 = csr[e + 1], e2 = csr[e + 2], e3 = csr[e + 3];
        uint32_t u0 = xb[(size_t)e0.x * 64];
        uint32_t u1 = xb[(size_t)e1.x * 64];
        uint32_t u2 = xb[(size_t)e2.x * 64];
        uint32_t u3 = xb[(size_t)e3.x * 64];
        float v0 = __int_as_float(e0.y), v1 = __int_as_float(e1.y);
        float v2 = __int_as_float(e2.y), v3 = __int_as_float(e3.y);
        alo0 = fmaf(v0, __uint_as_float(u0 << 16), alo0);
        ahi0 = fmaf(v0, __uint_as_float(u0 & 0xffff0000u), ahi0);
        alo1 = fmaf(v1, __uint_as_float(u1 << 16), alo1);
        ahi1 = fmaf(v1, __uint_as_float(u1 & 0xffff0000u), ahi1);
        alo2 = fmaf(v2, __uint_as_float(u2 << 16), alo2);
        ahi2 = fmaf(v2, __uint_as_float(u2 & 0xffff0000u), ahi2);
        alo3 = fmaf(v3, __uint_as_float(u3 << 16), alo3);
        ahi3 = fmaf(v3, __uint_as_float(u3 & 0xffff0000u), ahi3);
    }
    for (; e < end; ++e) {
        int2 e0 = csr[e];
        float v0 = __int_as_float(e0.y);
        uint32_t u0 = xb[(size_t)e0.x * 64];
        alo0 = fmaf(v0, __uint_as_float(u0 << 16), alo0);
        ahi0 = fmaf(v0, __uint_as_float(u0 & 0xffff0000u), ahi0);
    }
    float rlo = (alo0 + alo1) + (alo2 + alo3);
    float rhi = (ahi0 + ahi1) + (ahi2 + ahi3);
    if (RELU) { rlo = fmaxf(rlo, 0.f); rhi = fmaxf(rhi, 0.f); }
    outp[(size_t)r * 64 + lane] = pack_bf16x2(rlo, rhi);
}

// D=64: xp is [N][32] packed bf16x2; half-wave per edge; f32 output (final)
__global__ __launch_bounds__(256) void spmm_bf16_64(const int* __restrict__ row_ptr,
                                                    const int2* __restrict__ csr,
                                                    const uint32_t* __restrict__ xp,
                                                    float* __restrict__ out) {
    const int wid = threadIdx.x >> 6;
    const int lane = threadIdx.x & 63;
    const int r = blockIdx.x * 4 + wid;
    if (r >= N_NODES) return;
    const int start = row_ptr[r];
    const int end   = row_ptr[r + 1];
    const int j = lane & 31;
    const int half = lane >> 5;
    const uint32_t* xb = xp + j;

    float alo0 = 0.f, ahi0 = 0.f, alo1 = 0.f, ahi1 = 0.f;
    int e = start + half;
    for (; e + 2 < end; e += 4) {
        int2 ed0 = csr[e], ed1 = csr[e + 2];
        uint32_t u0 = xb[(size_t)ed0.x * 32];
        uint32_t u1 = xb[(size_t)ed1.x * 32];
        float v0 = __int_as_float(ed0.y), v1 = __int_as_float(ed1.y);
        alo0 = fmaf(v0, __uint_as_float(u0 << 16), alo0);
        ahi0 = fmaf(v0, __uint_as_float(u0 & 0xffff0000u), ahi0);
        alo1 = fmaf(v1, __uint_as_float(u1 << 16), alo1);
        ahi1 = fmaf(v1, __uint_as_float(u1 & 0xffff0000u), ahi1);
    }
    if (e < end) {
        int2 ed = csr[e];
        float v = __int_as_float(ed.y);
        uint32_t u = xb[(size_t)ed.x * 32];
        alo0 = fmaf(v, __uint_as_float(u << 16), alo0);
        ahi0 = fmaf(v, __uint_as_float(u & 0xffff0000u), ahi0);
    }
    float alo = alo0 + alo1, ahi = ahi0 + ahi1;
    alo += __shfl_xor(alo, 32);
    ahi += __shfl_xor(ahi, 32);
    if (half == 0) {
        float2 res = {alo, ahi};
        *reinterpret_cast<float2*>(out + (size_t)r * 64 + j * 2) = res;
    }
}

// ---------------- launch ----------------

extern "C" void kernel_launch(void* const* d_in, const int* in_sizes, int n_in,
                              void* d_out, int out_size, void* d_ws, size_t ws_size,
                              hipStream_t stream) {
    const float* x    = (const float*)d_in[0];
    const int*   row  = (const int*)  d_in[1];
    const int*   col  = (const int*)  d_in[2];
    const float* vals = (const float*)d_in[3];
    const float* W1   = (const float*)d_in[4];
    const float* W2   = (const float*)d_in[5];
    float* out = (float*)d_out;

    // workspace layout (256B-aligned chunks)
    char* ws = (char*)d_ws;
    auto align = [](size_t v) { return (v + 255) & ~(size_t)255; };
    int*      counts  = (int*)ws;              ws += align(sizeof(int) * N_NODES);
    int*      row_ptr = (int*)ws;              ws += align(sizeof(int) * (N_NODES + 1));
    int*      cursor  = (int*)ws;              ws += align(sizeof(int) * N_NODES);
    int*      bsum    = (int*)ws;              ws += align(sizeof(int) * SCAN_BLOCKS);
    int*      boff    = (int*)ws;              ws += align(sizeof(int) * SCAN_BLOCKS);
    int2*     csr     = (int2*)ws;             ws += align(sizeof(int2) * N_EDGES);
    uint32_t* tpk     = (uint32_t*)ws;         ws += align(sizeof(uint32_t) * N_NODES * 64);  // gemm1 out / gemm2 out
    uint32_t* hpk     = (uint32_t*)ws;         ws += align(sizeof(uint32_t) * N_NODES * 64);  // bf16 h
    unsigned short* wt1 = (unsigned short*)ws; ws += align(sizeof(short) * 128 * 128);
    unsigned short* wt2 = (unsigned short*)ws; ws += align(sizeof(short) * 64 * 128);

    // ---- CSR build (used by both layers) ----
    zero_ints<<<196, 256, 0, stream>>>(counts, N_NODES);
    hist_rows<<<1024, 256, 0, stream>>>(row, counts);
    scan_part<<<SCAN_BLOCKS, SCAN_THREADS, 0, stream>>>(counts, bsum);
    scan_bsum<<<1, 64, 0, stream>>>(bsum, boff);
    scan_final<<<SCAN_BLOCKS, SCAN_THREADS, 0, stream>>>(counts, boff, row_ptr, cursor);
    scatter_xcd<<<SCAT_BLOCKS_PER_XCD * XCD_GROUPS, 256, 0, stream>>>(row, col, vals, cursor, csr);

    // ---- weights -> bf16 transposed ----
    convert_wt<128, 128><<<(128 * 128 + 255) / 256, 256, 0, stream>>>(W1, wt1);
    convert_wt<128, 64><<<(64 * 128 + 255) / 256, 256, 0, stream>>>(W2, wt2);

    // ---- layer 1: t1 = bf16(x @ W1); h = bf16(relu(A @ t1)) ----
    gemm_mfma<HID_DIM, true><<<dim3(196, 2), 256, 0, stream>>>(x, nullptr, wt1, (unsigned short*)tpk);
    spmm_bf16_128<true><<<(N_NODES + 3) / 4, 256, 0, stream>>>(row_ptr, csr, tpk, hpk);

    // ---- layer 2: t2 = bf16(h @ W2); out = A @ t2 ----
    gemm_mfma<OUT_DIM, false><<<dim3(196, 1), 256, 0, stream>>>(nullptr, hpk, wt2, (unsigned short*)tpk);
    spmm_bf16_64<<<(N_NODES + 3) / 4, 256, 0, stream>>>(row_ptr, csr, tpk, out);
}

// Round 10
// 183.464 us; speedup vs baseline: 16.2085x; 1.0270x over previous
//
#include <hip/hip_runtime.h>
#include <stdint.h>

#define N_NODES 50000
#define N_EDGES 800000
#define IN_DIM 128
#define HID_DIM 128
#define OUT_DIM 64

#define SCAN_BLOCKS 64
#define SCAN_THREADS 256
#define SCAN_CH 4        // 64*256*4 = 65536 >= N_NODES

#define XCD_GROUPS 8
#define ROWS_PER_XCD (N_NODES / XCD_GROUPS)   // 6250 exactly
#define SCAT_BLOCKS_PER_XCD 128

typedef short bf16x8 __attribute__((ext_vector_type(8)));
typedef float f32x4  __attribute__((ext_vector_type(4)));

__device__ __forceinline__ uint32_t pack_bf16x2(float a, float b) {
    uint32_t ba = __float_as_uint(a), bb = __float_as_uint(b);
    ba = (ba + 0x7fffu + ((ba >> 16) & 1u)) >> 16;           // RNE low half
    bb = (bb + 0x7fffu + ((bb >> 16) & 1u)) & 0xffff0000u;   // RNE high half
    return ba | bb;
}

__device__ __forceinline__ unsigned short f2bf(float f) {
    uint32_t u = __float_as_uint(f);
    return (unsigned short)((u + 0x7fffu + ((u >> 16) & 1u)) >> 16);
}

// CSR entry: high 16 bits = bf16(val), low 16 bits = col (col < 65536)
__device__ __forceinline__ uint32_t pack_edge(int col, float v) {
    uint32_t fb = __float_as_uint(v);
    fb = (fb + 0x7fffu + ((fb >> 16) & 1u)) & 0xffff0000u;   // RNE bf16 in high half
    return fb | (uint32_t)col;
}

// ---------------- CSR build ----------------

__global__ void zero_ints(int* __restrict__ p, int n) {
    int i = blockIdx.x * blockDim.x + threadIdx.x;
    int stride = gridDim.x * blockDim.x;
    for (; i < n; i += stride) p[i] = 0;
}

__global__ void hist_rows(const int* __restrict__ row, int* __restrict__ counts) {
    int e = blockIdx.x * blockDim.x + threadIdx.x;
    int stride = gridDim.x * blockDim.x;
    for (; e < N_EDGES; e += stride) atomicAdd(&counts[row[e]], 1);
}

__global__ __launch_bounds__(SCAN_THREADS) void scan_part(const int* __restrict__ counts,
                                                          int* __restrict__ bsum) {
    __shared__ int red[SCAN_THREADS];
    const int b = blockIdx.x, t = threadIdx.x;
    const int base = (b * SCAN_THREADS + t) * SCAN_CH;
    int s = 0;
#pragma unroll
    for (int i = 0; i < SCAN_CH; ++i) {
        int idx = base + i;
        if (idx < N_NODES) s += counts[idx];
    }
    red[t] = s;
    __syncthreads();
#pragma unroll
    for (int off = SCAN_THREADS / 2; off > 0; off >>= 1) {
        if (t < off) red[t] += red[t + off];
        __syncthreads();
    }
    if (t == 0) bsum[b] = red[0];
}

// per-block rescan + write row_ptr / cursor; block prefix computed from bsum here
__global__ __launch_bounds__(SCAN_THREADS) void scan_final(const int* __restrict__ counts,
                                                           const int* __restrict__ bsum,
                                                           int* __restrict__ row_ptr,
                                                           int* __restrict__ cursor) {
    __shared__ int sums[SCAN_THREADS];
    __shared__ int sh_boff;
    const int b = blockIdx.x, t = threadIdx.x;
    if (t == 0) {
        int s = 0;
        for (int i = 0; i < b; ++i) s += bsum[i];   // 64 L2-hot loads max
        sh_boff = s;
    }
    const int base = (b * SCAN_THREADS + t) * SCAN_CH;
    int local[SCAN_CH];
    int s = 0;
#pragma unroll
    for (int i = 0; i < SCAN_CH; ++i) {
        int idx = base + i;
        int c = (idx < N_NODES) ? counts[idx] : 0;
        local[i] = c;
        s += c;
    }
    sums[t] = s;
    __syncthreads();
#pragma unroll
    for (int off = 1; off < SCAN_THREADS; off <<= 1) {
        int v = sums[t];
        int add = (t >= off) ? sums[t - off] : 0;
        __syncthreads();
        sums[t] = v + add;
        __syncthreads();
    }
    int run = sh_boff + sums[t] - s;
#pragma unroll
    for (int i = 0; i < SCAN_CH; ++i) {
        int idx = base + i;
        if (idx < N_NODES) {
            row_ptr[idx] = run;
            cursor[idx]  = run;
            run += local[i];
        }
    }
    if (b == 0 && t == 0) row_ptr[N_NODES] = N_EDGES;
}

// scatter edges into packed 4B CSR, XCD-partitioned destinations
__global__ __launch_bounds__(256) void scatter_xcd(const int* __restrict__ row,
                                                   const int* __restrict__ col,
                                                   const float* __restrict__ vals,
                                                   int* __restrict__ cursor,
                                                   uint32_t* __restrict__ csr) {
    const int xcd = blockIdx.x & (XCD_GROUPS - 1);
    const int blk = blockIdx.x >> 3;
    const int rlo = xcd * ROWS_PER_XCD;
    int e = blk * 256 + threadIdx.x;
    const int stride = SCAT_BLOCKS_PER_XCD * 256;
    for (; e < N_EDGES; e += stride) {
        int r = row[e];
        if ((unsigned)(r - rlo) < (unsigned)ROWS_PER_XCD) {
            int p = atomicAdd(&cursor[r], 1);
            csr[p] = pack_edge(col[e], vals[e]);
        }
    }
}

// ---------------- weights -> bf16 transposed (both in one launch) ----------------
// wt1[n*128+k] = bf16(W1[k*128+n]);  wt2[n*128+k] = bf16(W2[k*64+n])

__global__ void convert_w_both(const float* __restrict__ W1, const float* __restrict__ W2,
                               unsigned short* __restrict__ wt1, unsigned short* __restrict__ wt2) {
    int i = blockIdx.x * blockDim.x + threadIdx.x;
    if (i < 128 * 128) {
        int n = i >> 7, k = i & 127;
        wt1[i] = f2bf(W1[k * 128 + n]);
    } else if (i < 128 * 128 + 64 * 128) {
        int j = i - 128 * 128;
        int n = j >> 7, k = j & 127;
        wt2[j] = f2bf(W2[k * 64 + n]);
    }
}

// ---------------- MFMA GEMM: outb[M,N](bf16) = A[M,128] @ W[128,N] ----------------
// Per-wave: 16 B-frags loop-invariant in VGPRs; stream 16-row m-tiles.
// 16x16x32 bf16 MFMA layouts (HW-verified):
//   A: row=lane&15, k=(lane>>4)*8+j ; B from Wt[n][k]: col=lane&15, same k
//   D: col=lane&15, row=(lane>>4)*4+reg
// 50000 rows = 3125 m-tiles exactly.

template<int N, bool AF32>
__global__ __launch_bounds__(256) void gemm_mfma(const float* __restrict__ Af,
                                                 const uint32_t* __restrict__ Apk,
                                                 const unsigned short* __restrict__ Wt,
                                                 unsigned short* __restrict__ outb) {
    const int tid = threadIdx.x;
    const int wid = tid >> 6, lane = tid & 63;
    const int l15 = lane & 15, lk = lane >> 4;
    const int n0 = blockIdx.y * 64;

    bf16x8 bfrag[4][4];
#pragma unroll
    for (int t = 0; t < 4; ++t) {
        const unsigned short* wp = Wt + (size_t)(n0 + t * 16 + l15) * 128 + lk * 8;
#pragma unroll
        for (int s = 0; s < 4; ++s)
            bfrag[t][s] = *reinterpret_cast<const bf16x8*>(wp + s * 32);
    }

    for (int mt = blockIdx.x * 4 + wid; mt < 3125; mt += 784) {
        const int row = mt * 16 + l15;
        bf16x8 afrag[4];
        if (AF32) {
            const float* ap = Af + (size_t)row * 128 + lk * 8;
#pragma unroll
            for (int s = 0; s < 4; ++s) {
                float4 p0 = *reinterpret_cast<const float4*>(ap + s * 32);
                float4 p1 = *reinterpret_cast<const float4*>(ap + s * 32 + 4);
                bf16x8 f;
                f[0] = (short)f2bf(p0.x); f[1] = (short)f2bf(p0.y);
                f[2] = (short)f2bf(p0.z); f[3] = (short)f2bf(p0.w);
                f[4] = (short)f2bf(p1.x); f[5] = (short)f2bf(p1.y);
                f[6] = (short)f2bf(p1.z); f[7] = (short)f2bf(p1.w);
                afrag[s] = f;
            }
        } else {
            const uint32_t* ap = Apk + (size_t)row * 64 + lk * 4;
#pragma unroll
            for (int s = 0; s < 4; ++s)
                afrag[s] = *reinterpret_cast<const bf16x8*>(ap + s * 16);
        }

        f32x4 acc[4] = {{0.f,0.f,0.f,0.f},{0.f,0.f,0.f,0.f},{0.f,0.f,0.f,0.f},{0.f,0.f,0.f,0.f}};
#pragma unroll
        for (int s = 0; s < 4; ++s)
#pragma unroll
            for (int t = 0; t < 4; ++t)
                acc[t] = __builtin_amdgcn_mfma_f32_16x16x32_bf16(afrag[s], bfrag[t][s], acc[t], 0, 0, 0);

#pragma unroll
        for (int t = 0; t < 4; ++t)
#pragma unroll
            for (int q = 0; q < 4; ++q) {
                int r = mt * 16 + lk * 4 + q;
                outb[(size_t)r * N + n0 + t * 16 + l15] = f2bf(acc[t][q]);
            }
    }
}

// ---------------- CSR SPMM over bf16-packed operand, f32 accumulate ----------------

// D=128: xp is [N][64] packed bf16x2; lane = dims {2l,2l+1}; 8-edge unroll, 4 acc pairs.
// Output packed bf16 (feeds gemm2).
template<bool RELU>
__global__ __launch_bounds__(256) void spmm_bf16_128(const int* __restrict__ row_ptr,
                                                     const uint32_t* __restrict__ csr,
                                                     const uint32_t* __restrict__ xp,
                                                     uint32_t* __restrict__ outp) {
    const int wid = threadIdx.x >> 6;
    const int lane = threadIdx.x & 63;
    const int r = blockIdx.x * 4 + wid;
    if (r >= N_NODES) return;
    const int start = row_ptr[r];
    const int end   = row_ptr[r + 1];
    const uint32_t* xb = xp + lane;

    float alo[4] = {0.f, 0.f, 0.f, 0.f};
    float ahi[4] = {0.f, 0.f, 0.f, 0.f};
    int e = start;
    for (; e + 7 < end; e += 8) {
        uint32_t c0 = csr[e],     c1 = csr[e + 1], c2 = csr[e + 2], c3 = csr[e + 3];
        uint32_t c4 = csr[e + 4], c5 = csr[e + 5], c6 = csr[e + 6], c7 = csr[e + 7];
        uint32_t u0 = xb[(size_t)(c0 & 0xffffu) * 64];
        uint32_t u1 = xb[(size_t)(c1 & 0xffffu) * 64];
        uint32_t u2 = xb[(size_t)(c2 & 0xffffu) * 64];
        uint32_t u3 = xb[(size_t)(c3 & 0xffffu) * 64];
        uint32_t u4 = xb[(size_t)(c4 & 0xffffu) * 64];
        uint32_t u5 = xb[(size_t)(c5 & 0xffffu) * 64];
        uint32_t u6 = xb[(size_t)(c6 & 0xffffu) * 64];
        uint32_t u7 = xb[(size_t)(c7 & 0xffffu) * 64];
        float v0 = __uint_as_float(c0 & 0xffff0000u), v1 = __uint_as_float(c1 & 0xffff0000u);
        float v2 = __uint_as_float(c2 & 0xffff0000u), v3 = __uint_as_float(c3 & 0xffff0000u);
        float v4 = __uint_as_float(c4 & 0xffff0000u), v5 = __uint_as_float(c5 & 0xffff0000u);
        float v6 = __uint_as_float(c6 & 0xffff0000u), v7 = __uint_as_float(c7 & 0xffff0000u);
        alo[0] = fmaf(v0, __uint_as_float(u0 << 16), alo[0]);
        ahi[0] = fmaf(v0, __uint_as_float(u0 & 0xffff0000u), ahi[0]);
        alo[1] = fmaf(v1, __uint_as_float(u1 << 16), alo[1]);
        ahi[1] = fmaf(v1, __uint_as_float(u1 & 0xffff0000u), ahi[1]);
        alo[2] = fmaf(v2, __uint_as_float(u2 << 16), alo[2]);
        ahi[2] = fmaf(v2, __uint_as_float(u2 & 0xffff0000u), ahi[2]);
        alo[3] = fmaf(v3, __uint_as_float(u3 << 16), alo[3]);
        ahi[3] = fmaf(v3, __uint_as_float(u3 & 0xffff0000u), ahi[3]);
        alo[0] = fmaf(v4, __uint_as_float(u4 << 16), alo[0]);
        ahi[0] = fmaf(v4, __uint_as_float(u4 & 0xffff0000u), ahi[0]);
        alo[1] = fmaf(v5, __uint_as_float(u5 << 16), alo[1]);
        ahi[1] = fmaf(v5, __uint_as_float(u5 & 0xffff0000u), ahi[1]);
        alo[2] = fmaf(v6, __uint_as_float(u6 << 16), alo[2]);
        ahi[2] = fmaf(v6, __uint_as_float(u6 & 0xffff0000u), ahi[2]);
        alo[3] = fmaf(v7, __uint_as_float(u7 << 16), alo[3]);
        ahi[3] = fmaf(v7, __uint_as_float(u7 & 0xffff0000u), ahi[3]);
    }
    for (; e < end; ++e) {
        uint32_t c0 = csr[e];
        float v0 = __uint_as_float(c0 & 0xffff0000u);
        uint32_t u0 = xb[(size_t)(c0 & 0xffffu) * 64];
        alo[0] = fmaf(v0, __uint_as_float(u0 << 16), alo[0]);
        ahi[0] = fmaf(v0, __uint_as_float(u0 & 0xffff0000u), ahi[0]);
    }
    float rlo = (alo[0] + alo[1]) + (alo[2] + alo[3]);
    float rhi = (ahi[0] + ahi[1]) + (ahi[2] + ahi[3]);
    if (RELU) { rlo = fmaxf(rlo, 0.f); rhi = fmaxf(rhi, 0.f); }
    outp[(size_t)r * 64 + lane] = pack_bf16x2(rlo, rhi);
}

// D=64: xp is [N][32] packed bf16x2; half-wave per edge, 2-deep unroll per half
__global__ __launch_bounds__(256) void spmm_bf16_64(const int* __restrict__ row_ptr,
                                                    const uint32_t* __restrict__ csr,
                                                    const uint32_t* __restrict__ xp,
                                                    float* __restrict__ out) {
    const int wid = threadIdx.x >> 6;
    const int lane = threadIdx.x & 63;
    const int r = blockIdx.x * 4 + wid;
    if (r >= N_NODES) return;
    const int start = row_ptr[r];
    const int end   = row_ptr[r + 1];
    const int j = lane & 31;
    const int half = lane >> 5;
    const uint32_t* xb = xp + j;

    float alo0 = 0.f, ahi0 = 0.f, alo1 = 0.f, ahi1 = 0.f;
    int e = start + half;
    for (; e + 2 < end; e += 4) {
        uint32_t c0 = csr[e], c1 = csr[e + 2];
        uint32_t u0 = xb[(size_t)(c0 & 0xffffu) * 32];
        uint32_t u1 = xb[(size_t)(c1 & 0xffffu) * 32];
        float v0 = __uint_as_float(c0 & 0xffff0000u), v1 = __uint_as_float(c1 & 0xffff0000u);
        alo0 = fmaf(v0, __uint_as_float(u0 << 16), alo0);
        ahi0 = fmaf(v0, __uint_as_float(u0 & 0xffff0000u), ahi0);
        alo1 = fmaf(v1, __uint_as_float(u1 << 16), alo1);
        ahi1 = fmaf(v1, __uint_as_float(u1 & 0xffff0000u), ahi1);
    }
    if (e < end) {
        uint32_t c0 = csr[e];
        float v = __uint_as_float(c0 & 0xffff0000u);
        uint32_t u = xb[(size_t)(c0 & 0xffffu) * 32];
        alo0 = fmaf(v, __uint_as_float(u << 16), alo0);
        ahi0 = fmaf(v, __uint_as_float(u & 0xffff0000u), ahi0);
    }
    float alo = alo0 + alo1, ahi = ahi0 + ahi1;
    alo += __shfl_xor(alo, 32);
    ahi += __shfl_xor(ahi, 32);
    if (half == 0) {
        float2 res = {alo, ahi};
        *reinterpret_cast<float2*>(out + (size_t)r * 64 + j * 2) = res;
    }
}

// ---------------- launch ----------------

extern "C" void kernel_launch(void* const* d_in, const int* in_sizes, int n_in,
                              void* d_out, int out_size, void* d_ws, size_t ws_size,
                              hipStream_t stream) {
    const float* x    = (const float*)d_in[0];
    const int*   row  = (const int*)  d_in[1];
    const int*   col  = (const int*)  d_in[2];
    const float* vals = (const float*)d_in[3];
    const float* W1   = (const float*)d_in[4];
    const float* W2   = (const float*)d_in[5];
    float* out = (float*)d_out;

    // workspace layout (256B-aligned chunks)
    char* ws = (char*)d_ws;
    auto align = [](size_t v) { return (v + 255) & ~(size_t)255; };
    int*      counts  = (int*)ws;              ws += align(sizeof(int) * N_NODES);
    int*      row_ptr = (int*)ws;              ws += align(sizeof(int) * (N_NODES + 1));
    int*      cursor  = (int*)ws;              ws += align(sizeof(int) * N_NODES);
    int*      bsum    = (int*)ws;              ws += align(sizeof(int) * SCAN_BLOCKS);
    uint32_t* csr     = (uint32_t*)ws;         ws += align(sizeof(uint32_t) * N_EDGES);
    uint32_t* tpk     = (uint32_t*)ws;         ws += align(sizeof(uint32_t) * N_NODES * 64);  // gemm1/gemm2 out
    uint32_t* hpk     = (uint32_t*)ws;         ws += align(sizeof(uint32_t) * N_NODES * 64);  // bf16 h
    unsigned short* wt1 = (unsigned short*)ws; ws += align(sizeof(short) * 128 * 128);
    unsigned short* wt2 = (unsigned short*)ws; ws += align(sizeof(short) * 64 * 128);

    // ---- CSR build (used by both layers) ----
    zero_ints<<<196, 256, 0, stream>>>(counts, N_NODES);
    hist_rows<<<1024, 256, 0, stream>>>(row, counts);
    scan_part<<<SCAN_BLOCKS, SCAN_THREADS, 0, stream>>>(counts, bsum);
    scan_final<<<SCAN_BLOCKS, SCAN_THREADS, 0, stream>>>(counts, bsum, row_ptr, cursor);
    scatter_xcd<<<SCAT_BLOCKS_PER_XCD * XCD_GROUPS, 256, 0, stream>>>(row, col, vals, cursor, csr);

    // ---- weights -> bf16 transposed ----
    convert_w_both<<<(128 * 128 + 64 * 128 + 255) / 256, 256, 0, stream>>>(W1, W2, wt1, wt2);

    // ---- layer 1: t1 = bf16(x @ W1); h = bf16(relu(A @ t1)) ----
    gemm_mfma<HID_DIM, true><<<dim3(196, 2), 256, 0, stream>>>(x, nullptr, wt1, (unsigned short*)tpk);
    spmm_bf16_128<true><<<(N_NODES + 3) / 4, 256, 0, stream>>>(row_ptr, csr, tpk, hpk);

    // ---- layer 2: t2 = bf16(h @ W2); out = A @ t2 ----
    gemm_mfma<OUT_DIM, false><<<dim3(196, 1), 256, 0, stream>>>(nullptr, hpk, wt2, (unsigned short*)tpk);
    spmm_bf16_64<<<(N_NODES + 3) / 4, 256, 0, stream>>>(row_ptr, csr, tpk, out);
}